// Round 1
// baseline (253.391 us; speedup 1.0000x reference)
//
#include <hip/hip_runtime.h>
#include <hip/hip_bf16.h>

#define D_EMB 1024
#define T_LEN 4096

typedef short short8 __attribute__((ext_vector_type(8)));
typedef float f32x4 __attribute__((ext_vector_type(4)));
typedef float float4v __attribute__((ext_vector_type(4)));

__device__ __forceinline__ unsigned short f32_to_bf16(float f) {
    union { float f; unsigned int u; } c; c.f = f;
    unsigned int u = c.u;
    return (unsigned short)((u + 0x7FFFu + ((u >> 16) & 1u)) >> 16);
}

// ---------------- kernel 0: convert W (3 x 64x1024 fp32) -> bf16 Wb[192][1024]
__global__ __launch_bounds__(256) void convert_w(const float* __restrict__ Wk,
                                                 const float* __restrict__ Wq,
                                                 const float* __restrict__ Wv,
                                                 unsigned short* __restrict__ Wb) {
    int e = (blockIdx.x * 256 + threadIdx.x) * 8;  // 196608 total elems
    const float* src;
    if (e < 65536) src = Wk + e;
    else if (e < 131072) src = Wq + (e - 65536);
    else src = Wv + (e - 131072);
    float4v a0 = *(const float4v*)src;
    float4v a1 = *(const float4v*)(src + 4);
    short8 r;
    r[0] = (short)f32_to_bf16(a0[0]); r[1] = (short)f32_to_bf16(a0[1]);
    r[2] = (short)f32_to_bf16(a0[2]); r[3] = (short)f32_to_bf16(a0[3]);
    r[4] = (short)f32_to_bf16(a1[0]); r[5] = (short)f32_to_bf16(a1[1]);
    r[6] = (short)f32_to_bf16(a1[2]); r[7] = (short)f32_to_bf16(a1[3]);
    *(short8*)(Wb + e) = r;
}

// ---------------- kernel 1: QKV projection via MFMA
// C[16384 x 192] = X[16384 x 1024] * Wb^T.  Wb rows: 0..63=Wk, 64..127=Wq, 128..191=Wv
// Outputs: Kb (b,t,64) bf16; Qb (b,t,64) bf16; Vt (b,64,t) bf16 (transposed).
__global__ __launch_bounds__(256) void qkv_proj(const float* __restrict__ x,
                                                const unsigned short* __restrict__ Wb,
                                                unsigned short* __restrict__ Kb,
                                                unsigned short* __restrict__ Qb,
                                                unsigned short* __restrict__ Vt) {
    int lane = threadIdx.x & 63;
    int wave = threadIdx.x >> 6;
    int lo = lane & 15, hi = lane >> 4;
    int row0 = blockIdx.x * 64 + wave * 16;  // flat (b*T+t) row base of this wave

    const float* xrow = x + (size_t)(row0 + lo) * D_EMB + hi * 8;

    f32x4 acc[12];
#pragma unroll
    for (int n = 0; n < 12; n++) acc[n] = (f32x4){0.f, 0.f, 0.f, 0.f};

    for (int k0 = 0; k0 < D_EMB; k0 += 32) {
        float4v a0 = *(const float4v*)(xrow + k0);
        float4v a1 = *(const float4v*)(xrow + k0 + 4);
        short8 af;
        af[0] = (short)f32_to_bf16(a0[0]); af[1] = (short)f32_to_bf16(a0[1]);
        af[2] = (short)f32_to_bf16(a0[2]); af[3] = (short)f32_to_bf16(a0[3]);
        af[4] = (short)f32_to_bf16(a1[0]); af[5] = (short)f32_to_bf16(a1[1]);
        af[6] = (short)f32_to_bf16(a1[2]); af[7] = (short)f32_to_bf16(a1[3]);
#pragma unroll
        for (int n = 0; n < 12; n++) {
            short8 bf = *(const short8*)(Wb + (size_t)(16 * n + lo) * D_EMB + k0 + hi * 8);
            acc[n] = __builtin_amdgcn_mfma_f32_16x16x32_bf16(af, bf, acc[n], 0, 0, 0);
        }
    }

#pragma unroll
    for (int n = 0; n < 12; n++) {
        int h = (n & 3) * 16 + lo;
#pragma unroll
        for (int r = 0; r < 4; r++) {
            int g = row0 + hi * 4 + r;  // flat row
            unsigned short vb = f32_to_bf16(acc[n][r]);
            if (n < 4) {
                Kb[(size_t)g * 64 + h] = vb;
            } else if (n < 8) {
                Qb[(size_t)g * 64 + h] = vb;
            } else {
                int b = g >> 12, t = g & 4095;
                Vt[((size_t)b * 64 + h) * T_LEN + t] = vb;
            }
        }
    }
}

// ---------------- kernel 2: causal flash attention
// grid (T/64, B), block 256 (4 waves); wave w owns q rows qb0+16w..+15.
__global__ __launch_bounds__(256) void attn(const unsigned short* __restrict__ Qb,
                                            const unsigned short* __restrict__ Kb,
                                            const unsigned short* __restrict__ Vt,
                                            float* __restrict__ out) {
    __shared__ unsigned short Klds[64][72];      // keys x hdim, padded
    __shared__ unsigned short Vlds[64][72];      // hdim x keys (from Vt), padded
    __shared__ unsigned short Plds[4][16][72];   // per-wave P bounce

    int tid = threadIdx.x;
    int lane = tid & 63, wave = tid >> 6;
    int lo = lane & 15, hi = lane >> 4;
    int qb0 = blockIdx.x * 64;
    int b = blockIdx.y;
    size_t base = (size_t)b * T_LEN;

    // Q fragments (A-layout): lane holds Q[qrow=lo][k = 32c + hi*8 + j]
    const unsigned short* qg = Qb + (base + qb0 + wave * 16 + lo) * 64 + hi * 8;
    short8 qf0 = *(const short8*)qg;
    short8 qf1 = *(const short8*)(qg + 32);

    float m[4], lsum[4];
    f32x4 o[4];
#pragma unroll
    for (int r = 0; r < 4; r++) { m[r] = -1e30f; lsum[r] = 0.f; }
#pragma unroll
    for (int n = 0; n < 4; n++) o[n] = (f32x4){0.f, 0.f, 0.f, 0.f};

    int qrow_base = qb0 + wave * 16 + hi * 4;
    int wave_qmax = qb0 + wave * 16 + 15;
    const float L2E = 1.44269504f;

    for (int kv0 = 0; kv0 < qb0 + 64; kv0 += 64) {
        __syncthreads();
        for (int i = tid; i < 512; i += 256) {
            int row = i >> 3, c = i & 7;
            *(short8*)(&Klds[row][c * 8]) =
                *(const short8*)(Kb + (base + kv0 + row) * 64 + c * 8);
            *(short8*)(&Vlds[row][c * 8]) =
                *(const short8*)(Vt + ((size_t)b * 64 + row) * T_LEN + kv0 + c * 8);
        }
        __syncthreads();
        if (kv0 > wave_qmax) continue;  // wave-uniform; barriers already passed

        // S = Q K^T  (C-layout: row=hi*4+r, col=16cb+lo)
        f32x4 s[4];
#pragma unroll
        for (int cb = 0; cb < 4; cb++) s[cb] = (f32x4){0.f, 0.f, 0.f, 0.f};
#pragma unroll
        for (int cb = 0; cb < 4; cb++) {
            short8 k0f = *(const short8*)(&Klds[cb * 16 + lo][hi * 8]);
            short8 k1f = *(const short8*)(&Klds[cb * 16 + lo][32 + hi * 8]);
            s[cb] = __builtin_amdgcn_mfma_f32_16x16x32_bf16(qf0, k0f, s[cb], 0, 0, 0);
            s[cb] = __builtin_amdgcn_mfma_f32_16x16x32_bf16(qf1, k1f, s[cb], 0, 0, 0);
        }
        // scale + causal mask
#pragma unroll
        for (int cb = 0; cb < 4; cb++) {
            int key = kv0 + cb * 16 + lo;
#pragma unroll
            for (int r = 0; r < 4; r++) {
                float v = s[cb][r] * 0.125f;
                s[cb][r] = (key <= qrow_base + r) ? v : -1e30f;
            }
        }
        // online softmax
        float alpha[4];
#pragma unroll
        for (int r = 0; r < 4; r++) {
            float t0 = fmaxf(fmaxf(s[0][r], s[1][r]), fmaxf(s[2][r], s[3][r]));
            t0 = fmaxf(t0, __shfl_xor(t0, 1));
            t0 = fmaxf(t0, __shfl_xor(t0, 2));
            t0 = fmaxf(t0, __shfl_xor(t0, 4));
            t0 = fmaxf(t0, __shfl_xor(t0, 8));
            float mn = fmaxf(m[r], t0);
            alpha[r] = exp2f((m[r] - mn) * L2E);
            m[r] = mn;
        }
        float ps[4] = {0.f, 0.f, 0.f, 0.f};
#pragma unroll
        for (int cb = 0; cb < 4; cb++)
#pragma unroll
            for (int r = 0; r < 4; r++) {
                float p = exp2f((s[cb][r] - m[r]) * L2E);
                s[cb][r] = p;
                ps[r] += p;
            }
#pragma unroll
        for (int r = 0; r < 4; r++) {
            ps[r] += __shfl_xor(ps[r], 1);
            ps[r] += __shfl_xor(ps[r], 2);
            ps[r] += __shfl_xor(ps[r], 4);
            ps[r] += __shfl_xor(ps[r], 8);
            lsum[r] = lsum[r] * alpha[r] + ps[r];
        }
#pragma unroll
        for (int n = 0; n < 4; n++)
#pragma unroll
            for (int r = 0; r < 4; r++) o[n][r] *= alpha[r];
        // P -> LDS (bf16), re-enter A-layout
#pragma unroll
        for (int cb = 0; cb < 4; cb++)
#pragma unroll
            for (int r = 0; r < 4; r++)
                Plds[wave][hi * 4 + r][cb * 16 + lo] = f32_to_bf16(s[cb][r]);

        short8 pa0 = *(const short8*)(&Plds[wave][lo][hi * 8]);
        short8 pa1 = *(const short8*)(&Plds[wave][lo][32 + hi * 8]);
#pragma unroll
        for (int n = 0; n < 4; n++) {
            short8 v0f = *(const short8*)(&Vlds[n * 16 + lo][hi * 8]);
            short8 v1f = *(const short8*)(&Vlds[n * 16 + lo][32 + hi * 8]);
            o[n] = __builtin_amdgcn_mfma_f32_16x16x32_bf16(pa0, v0f, o[n], 0, 0, 0);
            o[n] = __builtin_amdgcn_mfma_f32_16x16x32_bf16(pa1, v1f, o[n], 0, 0, 0);
        }
    }

#pragma unroll
    for (int n = 0; n < 4; n++)
#pragma unroll
        for (int r = 0; r < 4; r++)
            out[(base + qrow_base + r) * 64 + n * 16 + lo] = o[n][r] / lsum[r];
}

extern "C" void kernel_launch(void* const* d_in, const int* in_sizes, int n_in,
                              void* d_out, int out_size, void* d_ws, size_t ws_size,
                              hipStream_t stream) {
    (void)in_sizes; (void)n_in; (void)out_size; (void)ws_size;
    const float* x  = (const float*)d_in[0];
    const float* Wk = (const float*)d_in[1];
    const float* Wq = (const float*)d_in[2];
    const float* Wv = (const float*)d_in[3];
    float* out = (float*)d_out;

    unsigned short* Wb = (unsigned short*)d_ws;          // 192*1024 bf16
    unsigned short* Kb = Wb + 192 * 1024;                // 16384*64
    unsigned short* Qb = Kb + 16384 * 64;
    unsigned short* Vt = Qb + 16384 * 64;                // (b,64,t)

    hipLaunchKernelGGL(convert_w, dim3(96), dim3(256), 0, stream, Wk, Wq, Wv, Wb);
    hipLaunchKernelGGL(qkv_proj, dim3(256), dim3(256), 0, stream, x, Wb, Kb, Qb, Vt);
    hipLaunchKernelGGL(attn, dim3(64, 4), dim3(256), 0, stream, Qb, Kb, Vt, out);
}

// Round 2
// 157.266 us; speedup vs baseline: 1.6112x; 1.6112x over previous
//
#include <hip/hip_runtime.h>
#include <hip/hip_bf16.h>

#define D_EMB 1024
#define T_LEN 4096

typedef short short8 __attribute__((ext_vector_type(8)));
typedef float f32x4 __attribute__((ext_vector_type(4)));
typedef float float4v __attribute__((ext_vector_type(4)));

__device__ __forceinline__ unsigned short f32_to_bf16(float f) {
    union { float f; unsigned int u; } c; c.f = f;
    unsigned int u = c.u;
    return (unsigned short)((u + 0x7FFFu + ((u >> 16) & 1u)) >> 16);
}

// ---------------- kernel 0: convert W (3 x 64x1024 fp32) -> bf16 Wb[192][1024]
__global__ __launch_bounds__(256) void convert_w(const float* __restrict__ Wk,
                                                 const float* __restrict__ Wq,
                                                 const float* __restrict__ Wv,
                                                 unsigned short* __restrict__ Wb) {
    int e = (blockIdx.x * 256 + threadIdx.x) * 8;
    const float* src;
    if (e < 65536) src = Wk + e;
    else if (e < 131072) src = Wq + (e - 65536);
    else src = Wv + (e - 131072);
    float4v a0 = *(const float4v*)src;
    float4v a1 = *(const float4v*)(src + 4);
    short8 r;
    r[0] = (short)f32_to_bf16(a0[0]); r[1] = (short)f32_to_bf16(a0[1]);
    r[2] = (short)f32_to_bf16(a0[2]); r[3] = (short)f32_to_bf16(a0[3]);
    r[4] = (short)f32_to_bf16(a1[0]); r[5] = (short)f32_to_bf16(a1[1]);
    r[6] = (short)f32_to_bf16(a1[2]); r[7] = (short)f32_to_bf16(a1[3]);
    *(short8*)(Wb + e) = r;
}

// ---------------- kernel 1: QKV projection, N split across blockIdx.y (0=K,1=Q,2=V)
__global__ __launch_bounds__(256) void qkv_proj(const float* __restrict__ x,
                                                const unsigned short* __restrict__ Wb,
                                                unsigned short* __restrict__ Kb,
                                                unsigned short* __restrict__ Qb,
                                                unsigned short* __restrict__ Vt) {
    __shared__ unsigned short Vtile[64][72];  // used only by grp==2

    int tid = threadIdx.x;
    int lane = tid & 63, wave = tid >> 6;
    int lo = lane & 15, hi = lane >> 4;
    int grp = blockIdx.y;
    int row0 = blockIdx.x * 64 + wave * 16;

    const float* xrow = x + (size_t)(row0 + lo) * D_EMB + hi * 8;

    f32x4 acc[4];
#pragma unroll
    for (int n = 0; n < 4; n++) acc[n] = (f32x4){0.f, 0.f, 0.f, 0.f};

    for (int k0 = 0; k0 < D_EMB; k0 += 32) {
        float4v a0 = *(const float4v*)(xrow + k0);
        float4v a1 = *(const float4v*)(xrow + k0 + 4);
        short8 af;
        af[0] = (short)f32_to_bf16(a0[0]); af[1] = (short)f32_to_bf16(a0[1]);
        af[2] = (short)f32_to_bf16(a0[2]); af[3] = (short)f32_to_bf16(a0[3]);
        af[4] = (short)f32_to_bf16(a1[0]); af[5] = (short)f32_to_bf16(a1[1]);
        af[6] = (short)f32_to_bf16(a1[2]); af[7] = (short)f32_to_bf16(a1[3]);
#pragma unroll
        for (int n = 0; n < 4; n++) {
            short8 bf = *(const short8*)(Wb + (size_t)(grp * 64 + 16 * n + lo) * D_EMB + k0 + hi * 8);
            acc[n] = __builtin_amdgcn_mfma_f32_16x16x32_bf16(af, bf, acc[n], 0, 0, 0);
        }
    }

    if (grp < 2) {
        unsigned short* dst = grp ? Qb : Kb;
#pragma unroll
        for (int n = 0; n < 4; n++)
#pragma unroll
            for (int r = 0; r < 4; r++)
                dst[(size_t)(row0 + hi * 4 + r) * 64 + n * 16 + lo] = f32_to_bf16(acc[n][r]);
    } else {
#pragma unroll
        for (int n = 0; n < 4; n++)
#pragma unroll
            for (int r = 0; r < 4; r++)
                Vtile[n * 16 + lo][wave * 16 + hi * 4 + r] = f32_to_bf16(acc[n][r]);
        __syncthreads();
        int b = (blockIdx.x * 64) >> 12;
        int t0 = (blockIdx.x * 64) & 4095;
        for (int u = tid; u < 512; u += 256) {
            int h = u >> 3, c = u & 7;
            *(short8*)(Vt + ((size_t)b * 64 + h) * T_LEN + t0 + c * 8) =
                *(const short8*)&Vtile[h][c * 8];
        }
    }
}

// ---------------- kernel 2: causal flash attention
// grid (T/32, B), block 256 = 4 waves. Block owns a 32-row Q tile; the 4 waves
// split the KV-tile range (mod 4, KVBLK=64) and merge (m,l,o) at the end.
// No barriers in the main loop; K/V fragments loaded directly from L2.
__global__ __launch_bounds__(256) void attn(const unsigned short* __restrict__ Qb,
                                            const unsigned short* __restrict__ Kb,
                                            const unsigned short* __restrict__ Vt,
                                            float* __restrict__ out) {
    __shared__ float oS[3][32][64];                 // waves 1..3 partial O
    __shared__ float mS[4][32], lS[4][32];
    __shared__ unsigned short Plds[4][2][16][72];   // per-wave P bounce

    int tid = threadIdx.x;
    int lane = tid & 63, wave = tid >> 6;
    int lo = lane & 15, hi = lane >> 4;
    int tile = blockIdx.x, b = blockIdx.y;
    int q0 = tile * 32;
    size_t base = (size_t)b * T_LEN;
    int K_tiles = (tile + 2) >> 1;  // ceil((32*tile+32)/64)
    const float L2E = 1.44269504f;

    short8 qf[2][2];
#pragma unroll
    for (int rb = 0; rb < 2; rb++)
#pragma unroll
        for (int kf = 0; kf < 2; kf++)
            qf[rb][kf] = *(const short8*)(Qb + (base + q0 + rb * 16 + lo) * 64 + kf * 32 + hi * 8);

    float m[2][4], l[2][4];
    f32x4 o[2][4];
#pragma unroll
    for (int rb = 0; rb < 2; rb++)
#pragma unroll
        for (int r = 0; r < 4; r++) { m[rb][r] = -1e30f; l[rb][r] = 0.f; }
#pragma unroll
    for (int rb = 0; rb < 2; rb++)
#pragma unroll
        for (int nb = 0; nb < 4; nb++) o[rb][nb] = (f32x4){0.f, 0.f, 0.f, 0.f};

    for (int j = wave; j < K_tiles; j += 4) {
        int kv0 = j * 64;
        short8 kfr[4][2], vfr[4][2];
#pragma unroll
        for (int cb = 0; cb < 4; cb++)
#pragma unroll
            for (int kf = 0; kf < 2; kf++)
                kfr[cb][kf] = *(const short8*)(Kb + (base + kv0 + cb * 16 + lo) * 64 + kf * 32 + hi * 8);
#pragma unroll
        for (int nb = 0; nb < 4; nb++)
#pragma unroll
            for (int kf = 0; kf < 2; kf++)
                vfr[nb][kf] = *(const short8*)(Vt + ((size_t)b * 64 + nb * 16 + lo) * T_LEN + kv0 + kf * 32 + hi * 8);

        f32x4 s[2][4];
#pragma unroll
        for (int rb = 0; rb < 2; rb++)
#pragma unroll
            for (int cb = 0; cb < 4; cb++) {
                f32x4 z = (f32x4){0.f, 0.f, 0.f, 0.f};
                z = __builtin_amdgcn_mfma_f32_16x16x32_bf16(qf[rb][0], kfr[cb][0], z, 0, 0, 0);
                z = __builtin_amdgcn_mfma_f32_16x16x32_bf16(qf[rb][1], kfr[cb][1], z, 0, 0, 0);
                s[rb][cb] = z;
            }

#pragma unroll
        for (int rb = 0; rb < 2; rb++) {
            float alpha[4];
#pragma unroll
            for (int r = 0; r < 4; r++) {
                int qrow = q0 + rb * 16 + hi * 4 + r;
#pragma unroll
                for (int cb = 0; cb < 4; cb++) {
                    int key = kv0 + cb * 16 + lo;
                    float v = s[rb][cb][r] * 0.125f;
                    s[rb][cb][r] = (key <= qrow) ? v : -1e30f;
                }
                float t0 = fmaxf(fmaxf(s[rb][0][r], s[rb][1][r]), fmaxf(s[rb][2][r], s[rb][3][r]));
                t0 = fmaxf(t0, __shfl_xor(t0, 1));
                t0 = fmaxf(t0, __shfl_xor(t0, 2));
                t0 = fmaxf(t0, __shfl_xor(t0, 4));
                t0 = fmaxf(t0, __shfl_xor(t0, 8));
                float mn = fmaxf(m[rb][r], t0);
                alpha[r] = exp2f((m[rb][r] - mn) * L2E);
                m[rb][r] = mn;
                float ps = 0.f;
#pragma unroll
                for (int cb = 0; cb < 4; cb++) {
                    float p = exp2f((s[rb][cb][r] - mn) * L2E);
                    s[rb][cb][r] = p;
                    ps += p;
                }
                ps += __shfl_xor(ps, 1);
                ps += __shfl_xor(ps, 2);
                ps += __shfl_xor(ps, 4);
                ps += __shfl_xor(ps, 8);
                l[rb][r] = l[rb][r] * alpha[r] + ps;
            }
#pragma unroll
            for (int nb = 0; nb < 4; nb++)
#pragma unroll
                for (int r = 0; r < 4; r++) o[rb][nb][r] *= alpha[r];
#pragma unroll
            for (int cb = 0; cb < 4; cb++)
#pragma unroll
                for (int r = 0; r < 4; r++)
                    Plds[wave][rb][hi * 4 + r][cb * 16 + lo] = f32_to_bf16(s[rb][cb][r]);
            short8 pa0 = *(const short8*)&Plds[wave][rb][lo][hi * 8];
            short8 pa1 = *(const short8*)&Plds[wave][rb][lo][32 + hi * 8];
#pragma unroll
            for (int nb = 0; nb < 4; nb++) {
                o[rb][nb] = __builtin_amdgcn_mfma_f32_16x16x32_bf16(pa0, vfr[nb][0], o[rb][nb], 0, 0, 0);
                o[rb][nb] = __builtin_amdgcn_mfma_f32_16x16x32_bf16(pa1, vfr[nb][1], o[rb][nb], 0, 0, 0);
            }
        }
    }

    // ---- merge the 4 waves' partials
    if (wave > 0) {
#pragma unroll
        for (int rb = 0; rb < 2; rb++)
#pragma unroll
            for (int nb = 0; nb < 4; nb++)
#pragma unroll
                for (int r = 0; r < 4; r++)
                    oS[wave - 1][rb * 16 + hi * 4 + r][nb * 16 + lo] = o[rb][nb][r];
    }
    if (lo == 0) {
#pragma unroll
        for (int rb = 0; rb < 2; rb++)
#pragma unroll
            for (int r = 0; r < 4; r++) {
                mS[wave][rb * 16 + hi * 4 + r] = m[rb][r];
                lS[wave][rb * 16 + hi * 4 + r] = l[rb][r];
            }
    }
    __syncthreads();
    if (wave == 0) {
#pragma unroll
        for (int rb = 0; rb < 2; rb++)
#pragma unroll
            for (int r = 0; r < 4; r++) {
                int rr = rb * 16 + hi * 4 + r;
                float mm = m[rb][r];
#pragma unroll
                for (int w = 1; w < 4; w++) mm = fmaxf(mm, mS[w][rr]);
                float a0 = exp2f((m[rb][r] - mm) * L2E);
                float ll = l[rb][r] * a0;
                float aw[3];
#pragma unroll
                for (int w = 1; w < 4; w++) {
                    aw[w - 1] = exp2f((mS[w][rr] - mm) * L2E);
                    ll += lS[w][rr] * aw[w - 1];
                }
                float inv = 1.f / ll;
#pragma unroll
                for (int nb = 0; nb < 4; nb++) {
                    float acc = o[rb][nb][r] * a0;
#pragma unroll
                    for (int w = 1; w < 4; w++)
                        acc += oS[w - 1][rr][nb * 16 + lo] * aw[w - 1];
                    out[(base + q0 + rr) * 64 + nb * 16 + lo] = acc * inv;
                }
            }
    }
}

extern "C" void kernel_launch(void* const* d_in, const int* in_sizes, int n_in,
                              void* d_out, int out_size, void* d_ws, size_t ws_size,
                              hipStream_t stream) {
    (void)in_sizes; (void)n_in; (void)out_size; (void)ws_size;
    const float* x  = (const float*)d_in[0];
    const float* Wk = (const float*)d_in[1];
    const float* Wq = (const float*)d_in[2];
    const float* Wv = (const float*)d_in[3];
    float* out = (float*)d_out;

    unsigned short* Wb = (unsigned short*)d_ws;          // 192*1024 bf16
    unsigned short* Kb = Wb + 192 * 1024;                // 16384*64
    unsigned short* Qb = Kb + 16384 * 64;
    unsigned short* Vt = Qb + 16384 * 64;                // (b,64,t)

    hipLaunchKernelGGL(convert_w, dim3(96), dim3(256), 0, stream, Wk, Wq, Wv, Wb);
    hipLaunchKernelGGL(qkv_proj, dim3(256, 3), dim3(256), 0, stream, x, Wb, Kb, Qb, Vt);
    hipLaunchKernelGGL(attn, dim3(128, 4), dim3(256), 0, stream, Qb, Kb, Vt, out);
}

// Round 3
// 130.334 us; speedup vs baseline: 1.9442x; 1.2066x over previous
//
#include <hip/hip_runtime.h>
#include <hip/hip_bf16.h>

#define D_EMB 1024
#define T_LEN 4096

typedef short short8 __attribute__((ext_vector_type(8)));
typedef float f32x4 __attribute__((ext_vector_type(4)));
typedef float float4v __attribute__((ext_vector_type(4)));

__device__ __forceinline__ unsigned short f32_to_bf16(float f) {
    union { float f; unsigned int u; } c; c.f = f;
    unsigned int u = c.u;
    return (unsigned short)((u + 0x7FFFu + ((u >> 16) & 1u)) >> 16);
}
__device__ __forceinline__ float bf16_to_f32(unsigned short v) {
    union { unsigned int u; float f; } c; c.u = ((unsigned int)v) << 16;
    return c.f;
}

// ---------------- kernel 0: convert W (3 x 64x1024 fp32) -> bf16 Wb[192][1024]
__global__ __launch_bounds__(256) void convert_w(const float* __restrict__ Wk,
                                                 const float* __restrict__ Wq,
                                                 const float* __restrict__ Wv,
                                                 unsigned short* __restrict__ Wb) {
    int e = (blockIdx.x * 256 + threadIdx.x) * 8;
    const float* src;
    if (e < 65536) src = Wk + e;
    else if (e < 131072) src = Wq + (e - 65536);
    else src = Wv + (e - 131072);
    float4v a0 = *(const float4v*)src;
    float4v a1 = *(const float4v*)(src + 4);
    short8 r;
    r[0] = (short)f32_to_bf16(a0[0]); r[1] = (short)f32_to_bf16(a0[1]);
    r[2] = (short)f32_to_bf16(a0[2]); r[3] = (short)f32_to_bf16(a0[3]);
    r[4] = (short)f32_to_bf16(a1[0]); r[5] = (short)f32_to_bf16(a1[1]);
    r[6] = (short)f32_to_bf16(a1[2]); r[7] = (short)f32_to_bf16(a1[3]);
    *(short8*)(Wb + e) = r;
}

// ---------------- kernel 1: one-pass QKV projection
// Block = 16 rows of x, 4 waves splitting K (1024) into 4 quarters.
// Each wave accumulates partial C[16 x 192]; merge through LDS.
// Q (cols 64..127) pre-scaled by 0.125. V stored transposed (b,64,t).
__global__ __launch_bounds__(256) void qkv_proj(const float* __restrict__ x,
                                                const unsigned short* __restrict__ Wb,
                                                unsigned short* __restrict__ Kb,
                                                unsigned short* __restrict__ Qb,
                                                unsigned short* __restrict__ Vt) {
    __shared__ float part[4][16][196];  // padded cols to de-conflict banks

    int tid = threadIdx.x;
    int lane = tid & 63, wave = tid >> 6;
    int lo = lane & 15, hi = lane >> 4;
    int row0 = blockIdx.x * 16;

    const float* xp = x + (size_t)(row0 + lo) * D_EMB + wave * 256 + hi * 8;

    f32x4 acc[12];
#pragma unroll
    for (int n = 0; n < 12; n++) acc[n] = (f32x4){0.f, 0.f, 0.f, 0.f};

    for (int ks = 0; ks < 8; ks++) {
        float4v a0 = *(const float4v*)(xp + ks * 32);
        float4v a1 = *(const float4v*)(xp + ks * 32 + 4);
        short8 af;
        af[0] = (short)f32_to_bf16(a0[0]); af[1] = (short)f32_to_bf16(a0[1]);
        af[2] = (short)f32_to_bf16(a0[2]); af[3] = (short)f32_to_bf16(a0[3]);
        af[4] = (short)f32_to_bf16(a1[0]); af[5] = (short)f32_to_bf16(a1[1]);
        af[6] = (short)f32_to_bf16(a1[2]); af[7] = (short)f32_to_bf16(a1[3]);
#pragma unroll
        for (int n = 0; n < 12; n++) {
            short8 bf = *(const short8*)(Wb + (size_t)(16 * n + lo) * D_EMB + wave * 256 + ks * 32 + hi * 8);
            acc[n] = __builtin_amdgcn_mfma_f32_16x16x32_bf16(af, bf, acc[n], 0, 0, 0);
        }
    }

#pragma unroll
    for (int n = 0; n < 12; n++)
#pragma unroll
        for (int r = 0; r < 4; r++)
            part[wave][hi * 4 + r][n * 16 + lo] = acc[n][r];
    __syncthreads();

    for (int u = tid; u < 384; u += 256) {
        int row = u / 24, ch = u % 24;
        float s8[8];
#pragma unroll
        for (int e = 0; e < 8; e++)
            s8[e] = part[0][row][ch * 8 + e] + part[1][row][ch * 8 + e] +
                    part[2][row][ch * 8 + e] + part[3][row][ch * 8 + e];
        if (ch < 16) {
            float sc = (ch >= 8) ? 0.125f : 1.0f;
            short8 v;
#pragma unroll
            for (int e = 0; e < 8; e++) v[e] = (short)f32_to_bf16(s8[e] * sc);
            unsigned short* dst = (ch < 8 ? Kb : Qb) + (size_t)(row0 + row) * 64 + (ch & 7) * 8;
            *(short8*)dst = v;
        } else {
            int b = row0 >> 12, t = (row0 + row) & 4095;
#pragma unroll
            for (int e = 0; e < 8; e++) {
                int h = (ch - 16) * 8 + e;
                Vt[((size_t)b * 64 + h) * T_LEN + t] = f32_to_bf16(s8[e]);
            }
        }
    }
}

// ---------------- kernel 2: causal flash attention (partial, 2-way KV split)
// 1D grid of 1024: u -> batch = u&3, v=u>>2, split=v&1, tile = 127-(v>>2 ... v>>1).
// blockId%8 == batch + 4*split -> each XCD touches exactly one batch (L2 affinity).
// Block = 32 q-rows, 4 waves interleave the split's KV tiles; partial (m,l,O) out.
__global__ __launch_bounds__(256) void attn(const unsigned short* __restrict__ Qb,
                                            const unsigned short* __restrict__ Kb,
                                            const unsigned short* __restrict__ Vt,
                                            unsigned short* __restrict__ Opart,
                                            float* __restrict__ Mpart,
                                            float* __restrict__ Lpart) {
    __shared__ float oS[3][32][64];
    __shared__ float mS[4][32], lS[4][32];
    __shared__ unsigned short Plds[4][2][16][72];

    int tid = threadIdx.x;
    int lane = tid & 63, wave = tid >> 6;
    int lo = lane & 15, hi = lane >> 4;

    unsigned int u = blockIdx.x;
    int b = u & 3;
    unsigned int v = u >> 2;
    int split = v & 1;
    int tile = 127 - (int)(v >> 1);  // heavy tiles dispatch first
    int q0 = tile * 32;
    size_t base = (size_t)b * T_LEN;
    int K_tiles = (tile + 2) >> 1;
    int H = (K_tiles + 1) >> 1;
    int j0 = split ? H : 0;
    int j1 = split ? K_tiles : H;
    const float L2E = 1.44269504f;

    short8 qf[2][2];
#pragma unroll
    for (int rb = 0; rb < 2; rb++)
#pragma unroll
        for (int kf = 0; kf < 2; kf++)
            qf[rb][kf] = *(const short8*)(Qb + (base + q0 + rb * 16 + lo) * 64 + kf * 32 + hi * 8);

    float m[2][4], l[2][4];
    f32x4 o[2][4];
#pragma unroll
    for (int rb = 0; rb < 2; rb++)
#pragma unroll
        for (int r = 0; r < 4; r++) { m[rb][r] = -1e30f; l[rb][r] = 0.f; }
#pragma unroll
    for (int rb = 0; rb < 2; rb++)
#pragma unroll
        for (int nb = 0; nb < 4; nb++) o[rb][nb] = (f32x4){0.f, 0.f, 0.f, 0.f};

    for (int j = j0 + wave; j < j1; j += 4) {
        int kv0 = j * 64;
        short8 kfr[4][2], vfr[4][2];
#pragma unroll
        for (int cb = 0; cb < 4; cb++)
#pragma unroll
            for (int kf = 0; kf < 2; kf++)
                kfr[cb][kf] = *(const short8*)(Kb + (base + kv0 + cb * 16 + lo) * 64 + kf * 32 + hi * 8);
#pragma unroll
        for (int nb = 0; nb < 4; nb++)
#pragma unroll
            for (int kf = 0; kf < 2; kf++)
                vfr[nb][kf] = *(const short8*)(Vt + ((size_t)b * 64 + nb * 16 + lo) * T_LEN + kv0 + kf * 32 + hi * 8);

        f32x4 s[2][4];
#pragma unroll
        for (int rb = 0; rb < 2; rb++)
#pragma unroll
            for (int cb = 0; cb < 4; cb++) {
                f32x4 z = (f32x4){0.f, 0.f, 0.f, 0.f};
                z = __builtin_amdgcn_mfma_f32_16x16x32_bf16(qf[rb][0], kfr[cb][0], z, 0, 0, 0);
                z = __builtin_amdgcn_mfma_f32_16x16x32_bf16(qf[rb][1], kfr[cb][1], z, 0, 0, 0);
                s[rb][cb] = z;
            }

#pragma unroll
        for (int rb = 0; rb < 2; rb++) {
            float alpha[4];
#pragma unroll
            for (int r = 0; r < 4; r++) {
                int qrow = q0 + rb * 16 + hi * 4 + r;
#pragma unroll
                for (int cb = 0; cb < 4; cb++) {
                    int key = kv0 + cb * 16 + lo;
                    s[rb][cb][r] = (key <= qrow) ? s[rb][cb][r] : -1e30f;
                }
                float t0 = fmaxf(fmaxf(s[rb][0][r], s[rb][1][r]), fmaxf(s[rb][2][r], s[rb][3][r]));
                t0 = fmaxf(t0, __shfl_xor(t0, 1));
                t0 = fmaxf(t0, __shfl_xor(t0, 2));
                t0 = fmaxf(t0, __shfl_xor(t0, 4));
                t0 = fmaxf(t0, __shfl_xor(t0, 8));
                float mn = fmaxf(m[rb][r], t0);
                alpha[r] = exp2f((m[rb][r] - mn) * L2E);
                m[rb][r] = mn;
                float ps = 0.f;
#pragma unroll
                for (int cb = 0; cb < 4; cb++) {
                    float p = exp2f((s[rb][cb][r] - mn) * L2E);
                    s[rb][cb][r] = p;
                    ps += p;
                }
                ps += __shfl_xor(ps, 1);
                ps += __shfl_xor(ps, 2);
                ps += __shfl_xor(ps, 4);
                ps += __shfl_xor(ps, 8);
                l[rb][r] = l[rb][r] * alpha[r] + ps;
            }
#pragma unroll
            for (int nb = 0; nb < 4; nb++)
#pragma unroll
                for (int r = 0; r < 4; r++) o[rb][nb][r] *= alpha[r];
#pragma unroll
            for (int cb = 0; cb < 4; cb++)
#pragma unroll
                for (int r = 0; r < 4; r++)
                    Plds[wave][rb][hi * 4 + r][cb * 16 + lo] = f32_to_bf16(s[rb][cb][r]);
            short8 pa0 = *(const short8*)&Plds[wave][rb][lo][hi * 8];
            short8 pa1 = *(const short8*)&Plds[wave][rb][lo][32 + hi * 8];
#pragma unroll
            for (int nb = 0; nb < 4; nb++) {
                o[rb][nb] = __builtin_amdgcn_mfma_f32_16x16x32_bf16(pa0, vfr[nb][0], o[rb][nb], 0, 0, 0);
                o[rb][nb] = __builtin_amdgcn_mfma_f32_16x16x32_bf16(pa1, vfr[nb][1], o[rb][nb], 0, 0, 0);
            }
        }
    }

    // ---- merge the 4 waves' partials -> block partial (unnormalized)
    if (wave > 0) {
#pragma unroll
        for (int rb = 0; rb < 2; rb++)
#pragma unroll
            for (int nb = 0; nb < 4; nb++)
#pragma unroll
                for (int r = 0; r < 4; r++)
                    oS[wave - 1][rb * 16 + hi * 4 + r][nb * 16 + lo] = o[rb][nb][r];
    }
    if (lo == 0) {
#pragma unroll
        for (int rb = 0; rb < 2; rb++)
#pragma unroll
            for (int r = 0; r < 4; r++) {
                mS[wave][rb * 16 + hi * 4 + r] = m[rb][r];
                lS[wave][rb * 16 + hi * 4 + r] = l[rb][r];
            }
    }
    __syncthreads();
    if (wave == 0) {
        size_t pbase = ((size_t)split * 4 + b) * T_LEN;
#pragma unroll
        for (int rb = 0; rb < 2; rb++)
#pragma unroll
            for (int r = 0; r < 4; r++) {
                int rr = rb * 16 + hi * 4 + r;
                float mm = m[rb][r];
#pragma unroll
                for (int w = 1; w < 4; w++) mm = fmaxf(mm, mS[w][rr]);
                float a0 = exp2f((m[rb][r] - mm) * L2E);
                float ll = l[rb][r] * a0;
                float aw[3];
#pragma unroll
                for (int w = 1; w < 4; w++) {
                    aw[w - 1] = exp2f((mS[w][rr] - mm) * L2E);
                    ll += lS[w][rr] * aw[w - 1];
                }
#pragma unroll
                for (int nb = 0; nb < 4; nb++) {
                    float acc = o[rb][nb][r] * a0;
#pragma unroll
                    for (int w = 1; w < 4; w++)
                        acc += oS[w - 1][rr][nb * 16 + lo] * aw[w - 1];
                    Opart[(pbase + q0 + rr) * 64 + nb * 16 + lo] = f32_to_bf16(acc);
                }
                if (lo == 0) {
                    Mpart[pbase + q0 + rr] = mm;
                    Lpart[pbase + q0 + rr] = ll;
                }
            }
    }
}

// ---------------- kernel 3: merge the 2 KV-split partials
__global__ __launch_bounds__(256) void attn_merge(const unsigned short* __restrict__ Opart,
                                                  const float* __restrict__ Mpart,
                                                  const float* __restrict__ Lpart,
                                                  float* __restrict__ out) {
    const float L2E = 1.44269504f;
    int g = blockIdx.x * 64 + (threadIdx.x >> 2);
    int c0 = (threadIdx.x & 3) * 16;
    float m0 = Mpart[g], m1 = Mpart[16384 + g];
    float l0 = Lpart[g], l1 = Lpart[16384 + g];
    float mm = fmaxf(m0, m1);
    float a0 = exp2f((m0 - mm) * L2E);
    float a1 = exp2f((m1 - mm) * L2E);
    float inv = 1.f / (a0 * l0 + a1 * l1);
    const unsigned short* p0 = Opart + (size_t)g * 64 + c0;
    const unsigned short* p1 = Opart + (size_t)16384 * 64 + (size_t)g * 64 + c0;
    short8 v0a = *(const short8*)p0, v0b = *(const short8*)(p0 + 8);
    short8 v1a = *(const short8*)p1, v1b = *(const short8*)(p1 + 8);
    float* dst = out + (size_t)g * 64 + c0;
#pragma unroll
    for (int e = 0; e < 8; e++) {
        dst[e]     = (a0 * bf16_to_f32((unsigned short)v0a[e]) + a1 * bf16_to_f32((unsigned short)v1a[e])) * inv;
        dst[e + 8] = (a0 * bf16_to_f32((unsigned short)v0b[e]) + a1 * bf16_to_f32((unsigned short)v1b[e])) * inv;
    }
}

extern "C" void kernel_launch(void* const* d_in, const int* in_sizes, int n_in,
                              void* d_out, int out_size, void* d_ws, size_t ws_size,
                              hipStream_t stream) {
    (void)in_sizes; (void)n_in; (void)out_size; (void)ws_size;
    const float* x  = (const float*)d_in[0];
    const float* Wk = (const float*)d_in[1];
    const float* Wq = (const float*)d_in[2];
    const float* Wv = (const float*)d_in[3];
    float* out = (float*)d_out;

    unsigned short* Wb = (unsigned short*)d_ws;          // 192*1024
    unsigned short* Kb = Wb + 192 * 1024;                // 16384*64
    unsigned short* Qb = Kb + 16384 * 64;                // pre-scaled by 0.125
    unsigned short* Vt = Qb + 16384 * 64;                // (b,64,t)
    unsigned short* Opart = Vt + 16384 * 64;             // [2][16384][64] bf16
    float* Mpart = (float*)(Opart + (size_t)2 * 16384 * 64);  // [2][16384]
    float* Lpart = Mpart + 2 * 16384;

    hipLaunchKernelGGL(convert_w, dim3(96), dim3(256), 0, stream, Wk, Wq, Wv, Wb);
    hipLaunchKernelGGL(qkv_proj, dim3(1024), dim3(256), 0, stream, x, Wb, Kb, Qb, Vt);
    hipLaunchKernelGGL(attn, dim3(1024), dim3(256), 0, stream, Qb, Kb, Vt, Opart, Mpart, Lpart);
    hipLaunchKernelGGL(attn_merge, dim3(256), dim3(256), 0, stream, Opart, Mpart, Lpart, out);
}

// Round 4
// 108.770 us; speedup vs baseline: 2.3296x; 1.1983x over previous
//
#include <hip/hip_runtime.h>
#include <hip/hip_bf16.h>

#define D_EMB 1024
#define T_LEN 4096
#define NTASK 576  // attn tasks per batch (sum of ceil((t+1)/16), t=0..127)

typedef short short8 __attribute__((ext_vector_type(8)));
typedef float f32x4 __attribute__((ext_vector_type(4)));
typedef float f32x16 __attribute__((ext_vector_type(16)));
typedef float float4v __attribute__((ext_vector_type(4)));

__device__ __forceinline__ unsigned short f32_to_bf16(float f) {
    union { float f; unsigned int u; } c; c.f = f;
    unsigned int u = c.u;
    return (unsigned short)((u + 0x7FFFu + ((u >> 16) & 1u)) >> 16);
}
__device__ __forceinline__ float bf16_to_f32(unsigned short v) {
    union { unsigned int u; float f; } c; c.u = ((unsigned int)v) << 16;
    return c.f;
}

// scale folded into Q: 1/sqrt(64) * log2(e)  (softmax done in exp2 domain)
#define QSCALE (0.125f * 1.44269504f)

// ---------------- kernel 0: convert W (3 x 64x1024 fp32) -> bf16 Wb[192][1024]
__global__ __launch_bounds__(256) void convert_w(const float* __restrict__ Wk,
                                                 const float* __restrict__ Wq,
                                                 const float* __restrict__ Wv,
                                                 unsigned short* __restrict__ Wb) {
    int e = (blockIdx.x * 256 + threadIdx.x) * 8;
    const float* src;
    if (e < 65536) src = Wk + e;
    else if (e < 131072) src = Wq + (e - 65536);
    else src = Wv + (e - 131072);
    float4v a0 = *(const float4v*)src;
    float4v a1 = *(const float4v*)(src + 4);
    short8 r;
    r[0] = (short)f32_to_bf16(a0[0]); r[1] = (short)f32_to_bf16(a0[1]);
    r[2] = (short)f32_to_bf16(a0[2]); r[3] = (short)f32_to_bf16(a0[3]);
    r[4] = (short)f32_to_bf16(a1[0]); r[5] = (short)f32_to_bf16(a1[1]);
    r[6] = (short)f32_to_bf16(a1[2]); r[7] = (short)f32_to_bf16(a1[3]);
    *(short8*)(Wb + e) = r;
}

// ---------------- kernel 1: QKV projection. BM=32 rows/block, 4 waves:
// wave (rw,kw): rows [row0+16rw,+16), K half [512kw,+512). LDS merge at end.
__global__ __launch_bounds__(256) void qkv_proj(const float* __restrict__ x,
                                                const unsigned short* __restrict__ Wb,
                                                unsigned short* __restrict__ Kb,
                                                unsigned short* __restrict__ Qb,
                                                unsigned short* __restrict__ Vt) {
    __shared__ float part[2][2][16][196];

    int tid = threadIdx.x;
    int lane = tid & 63, wave = tid >> 6;
    int lo = lane & 15, hi = lane >> 4;
    int rw = wave >> 1, kw = wave & 1;
    int row0 = blockIdx.x * 32;

    const float* xp = x + (size_t)(row0 + rw * 16 + lo) * D_EMB + kw * 512 + hi * 8;
    const unsigned short* wp = Wb + (size_t)lo * D_EMB + kw * 512 + hi * 8;

    f32x4 acc[12];
#pragma unroll
    for (int n = 0; n < 12; n++) acc[n] = (f32x4){0.f, 0.f, 0.f, 0.f};

    for (int ks = 0; ks < 16; ks++) {
        float4v a0 = *(const float4v*)(xp + ks * 32);
        float4v a1 = *(const float4v*)(xp + ks * 32 + 4);
        short8 af;
        af[0] = (short)f32_to_bf16(a0[0]); af[1] = (short)f32_to_bf16(a0[1]);
        af[2] = (short)f32_to_bf16(a0[2]); af[3] = (short)f32_to_bf16(a0[3]);
        af[4] = (short)f32_to_bf16(a1[0]); af[5] = (short)f32_to_bf16(a1[1]);
        af[6] = (short)f32_to_bf16(a1[2]); af[7] = (short)f32_to_bf16(a1[3]);
#pragma unroll
        for (int n = 0; n < 12; n++) {
            short8 bf = *(const short8*)(wp + (size_t)n * 16 * D_EMB + ks * 32);
            acc[n] = __builtin_amdgcn_mfma_f32_16x16x32_bf16(af, bf, acc[n], 0, 0, 0);
        }
    }

#pragma unroll
    for (int n = 0; n < 12; n++)
#pragma unroll
        for (int r = 0; r < 4; r++)
            part[rw][kw][hi * 4 + r][n * 16 + lo] = acc[n][r];
    __syncthreads();

    for (int u = tid; u < 768; u += 256) {
        int rr = u / 24, ch = u % 24;
        float s8[8];
#pragma unroll
        for (int e = 0; e < 8; e++)
            s8[e] = part[rr >> 4][0][rr & 15][ch * 8 + e] +
                    part[rr >> 4][1][rr & 15][ch * 8 + e];
        int grow = row0 + rr;
        if (ch < 8) {
            short8 v;
#pragma unroll
            for (int e = 0; e < 8; e++) v[e] = (short)f32_to_bf16(s8[e]);
            *(short8*)(Kb + (size_t)grow * 64 + ch * 8) = v;
        } else if (ch < 16) {
            short8 v;
#pragma unroll
            for (int e = 0; e < 8; e++) v[e] = (short)f32_to_bf16(s8[e] * QSCALE);
            *(short8*)(Qb + (size_t)grow * 64 + (ch - 8) * 8) = v;
        } else {
            int b = grow >> 12, trow = grow & 4095;
#pragma unroll
            for (int e = 0; e < 8; e++)
                Vt[((size_t)b * 64 + (ch - 16) * 8 + e) * T_LEN + trow] = f32_to_bf16(s8[e]);
        }
    }
}

// ---------------- kernel 2: causal flash attention, 1 wave per task.
// Task = (tile of 32 q-rows, chunk of <=512 keys). Swapped QK^T via 32x32x16
// MFMA: S^T col = q = lane&31 (lane-local softmax state). PV accumulates O^T.
// No LDS, no barriers. Partials (m, l, O) out; merged by attn_merge.
__global__ __launch_bounds__(64, 3) void attn(const unsigned short* __restrict__ Qb,
                                              const unsigned short* __restrict__ Kb,
                                              const unsigned short* __restrict__ Vt,
                                              unsigned short* __restrict__ Opart,
                                              float* __restrict__ Mpart,
                                              float* __restrict__ Lpart) {
    int lane = threadIdx.x;
    int q32 = lane & 31;
    int hi = lane >> 5;
    int s = blockIdx.x;   // 0..575, heavy tiles first
    int b = blockIdx.y;

    // decode (tile t, chunk c): group k has tiles [16k,16k+15], k+1 chunks each
    int k = 7, rem = s;
    while (rem >= 16 * (k + 1)) { rem -= 16 * (k + 1); k--; }
    int cpt = k + 1;
    int ti = rem / cpt;
    int t = (k << 4) + 15 - ti;
    int c = rem - ti * cpt;

    int u0 = c * 16;
    int u1 = min(u0 + 16, t + 1);   // 32-key units

    size_t base = (size_t)b * T_LEN;
    int q0 = t * 32;
    int qg = q0 + q32;

    // Q B-fragments (col=q=lane&31, k-rows d = 16*ds + 8*hi + j)
    short8 qf[4];
    const unsigned short* qp = Qb + (base + qg) * 64 + hi * 8;
#pragma unroll
    for (int d = 0; d < 4; d++) qf[d] = *(const short8*)(qp + d * 16);

    size_t vbase = ((size_t)b * 64 + q32) * T_LEN;
    f32x16 o0 = {0.f}, o1 = {0.f};
    float m = -3e38f, l = 0.f;

    for (int u = u0; u < u1; ++u) {
        int kv0 = u * 32;
        const unsigned short* kp = Kb + (base + kv0 + q32) * 64 + hi * 8;
        short8 kf0 = *(const short8*)kp;
        short8 kf1 = *(const short8*)(kp + 16);
        short8 kf2 = *(const short8*)(kp + 32);
        short8 kf3 = *(const short8*)(kp + 48);
        const unsigned short* vp = Vt + vbase + kv0 + hi * 8;
        short8 vf00 = *(const short8*)vp;
        short8 vf01 = *(const short8*)(vp + 16);
        short8 vf10 = *(const short8*)(vp + 32 * T_LEN);
        short8 vf11 = *(const short8*)(vp + 32 * T_LEN + 16);

        // S^T = K * Q^T : col = q (lane&31), row k = (r&3)+8*(r>>2)+4*hi
        f32x16 sc = {0.f};
        sc = __builtin_amdgcn_mfma_f32_32x32x16_bf16(kf0, qf[0], sc, 0, 0, 0);
        sc = __builtin_amdgcn_mfma_f32_32x32x16_bf16(kf1, qf[1], sc, 0, 0, 0);
        sc = __builtin_amdgcn_mfma_f32_32x32x16_bf16(kf2, qf[2], sc, 0, 0, 0);
        sc = __builtin_amdgcn_mfma_f32_32x32x16_bf16(kf3, qf[3], sc, 0, 0, 0);

        if (u == t) {  // diagonal unit: causal mask
#pragma unroll
            for (int r = 0; r < 16; ++r) {
                int ko = (r & 3) + 8 * (r >> 2) + 4 * hi;
                sc[r] = (ko <= q32) ? sc[r] : -3e38f;
            }
        }

        // row max: tree over 16 regs + one cross-half exchange
        float x0 = fmaxf(sc[0], sc[8]),  x1 = fmaxf(sc[1], sc[9]);
        float x2 = fmaxf(sc[2], sc[10]), x3 = fmaxf(sc[3], sc[11]);
        float x4 = fmaxf(sc[4], sc[12]), x5 = fmaxf(sc[5], sc[13]);
        float x6 = fmaxf(sc[6], sc[14]), x7 = fmaxf(sc[7], sc[15]);
        x0 = fmaxf(x0, x4); x1 = fmaxf(x1, x5); x2 = fmaxf(x2, x6); x3 = fmaxf(x3, x7);
        x0 = fmaxf(x0, x2); x1 = fmaxf(x1, x3);
        float mx = fmaxf(x0, x1);
        mx = fmaxf(mx, __shfl_xor(mx, 32));

        // defer-max (THR=8): skip O-rescale when max barely grew
        if (__any(mx > m + 8.0f)) {
            float mn = fmaxf(m, mx);
            float al = exp2f(m - mn);
            m = mn; l *= al;
#pragma unroll
            for (int r = 0; r < 16; ++r) { o0[r] *= al; o1[r] *= al; }
        }

#pragma unroll
        for (int r = 0; r < 16; ++r) sc[r] = exp2f(sc[r] - m);
        float y0 = (sc[0] + sc[8]) + (sc[4] + sc[12]);
        float y1 = (sc[1] + sc[9]) + (sc[5] + sc[13]);
        float y2 = (sc[2] + sc[10]) + (sc[6] + sc[14]);
        float y3 = (sc[3] + sc[11]) + (sc[7] + sc[15]);
        float sum = (y0 + y1) + (y2 + y3);
        sum += __shfl_xor(sum, 32);
        l += sum;

        // pack P -> bf16 PV B-fragments (cvt_pk + permlane32_swap, guide T12)
        unsigned bb0, bb1, bb2, bb3, bb4, bb5, bb6, bb7;
        asm("v_cvt_pk_bf16_f32 %0, %1, %2" : "=v"(bb0) : "v"(sc[0]),  "v"(sc[1]));
        asm("v_cvt_pk_bf16_f32 %0, %1, %2" : "=v"(bb1) : "v"(sc[2]),  "v"(sc[3]));
        asm("v_cvt_pk_bf16_f32 %0, %1, %2" : "=v"(bb2) : "v"(sc[4]),  "v"(sc[5]));
        asm("v_cvt_pk_bf16_f32 %0, %1, %2" : "=v"(bb3) : "v"(sc[6]),  "v"(sc[7]));
        asm("v_cvt_pk_bf16_f32 %0, %1, %2" : "=v"(bb4) : "v"(sc[8]),  "v"(sc[9]));
        asm("v_cvt_pk_bf16_f32 %0, %1, %2" : "=v"(bb5) : "v"(sc[10]), "v"(sc[11]));
        asm("v_cvt_pk_bf16_f32 %0, %1, %2" : "=v"(bb6) : "v"(sc[12]), "v"(sc[13]));
        asm("v_cvt_pk_bf16_f32 %0, %1, %2" : "=v"(bb7) : "v"(sc[14]), "v"(sc[15]));
        asm("v_permlane32_swap_b32 %0, %1" : "+v"(bb0), "+v"(bb2));
        asm("v_permlane32_swap_b32 %0, %1" : "+v"(bb1), "+v"(bb3));
        asm("v_permlane32_swap_b32 %0, %1" : "+v"(bb4), "+v"(bb6));
        asm("v_permlane32_swap_b32 %0, %1" : "+v"(bb5), "+v"(bb7));
        union U8 { unsigned u[4]; short8 s; };
        U8 p0; p0.u[0] = bb0; p0.u[1] = bb1; p0.u[2] = bb2; p0.u[3] = bb3;
        U8 p1; p1.u[0] = bb4; p1.u[1] = bb5; p1.u[2] = bb6; p1.u[3] = bb7;

        // O^T += V^T * P^T  (col = q, rows = h)
        o0 = __builtin_amdgcn_mfma_f32_32x32x16_bf16(vf00, p0.s, o0, 0, 0, 0);
        o0 = __builtin_amdgcn_mfma_f32_32x32x16_bf16(vf01, p1.s, o0, 0, 0, 0);
        o1 = __builtin_amdgcn_mfma_f32_32x32x16_bf16(vf10, p0.s, o1, 0, 0, 0);
        o1 = __builtin_amdgcn_mfma_f32_32x32x16_bf16(vf11, p1.s, o1, 0, 0, 0);
    }

    // store partial: Opart[(b*NTASK+s)][q32][h] bf16
    size_t tbase = ((size_t)(b * NTASK + s) * 32 + q32) * 64;
#pragma unroll
    for (int hb = 0; hb < 2; hb++) {
#pragma unroll
        for (int g = 0; g < 4; g++) {
            float e0 = hb ? o1[4 * g] : o0[4 * g];
            float e1 = hb ? o1[4 * g + 1] : o0[4 * g + 1];
            float e2 = hb ? o1[4 * g + 2] : o0[4 * g + 2];
            float e3 = hb ? o1[4 * g + 3] : o0[4 * g + 3];
            unsigned w0, w1;
            asm("v_cvt_pk_bf16_f32 %0, %1, %2" : "=v"(w0) : "v"(e0), "v"(e1));
            asm("v_cvt_pk_bf16_f32 %0, %1, %2" : "=v"(w1) : "v"(e2), "v"(e3));
            int h0 = hb * 32 + g * 8 + hi * 4;
            *reinterpret_cast<uint2*>(Opart + tbase + h0) = make_uint2(w0, w1);
        }
    }
    if (lane < 32) {
        Mpart[(b * NTASK + s) * 32 + q32] = m;
        Lpart[(b * NTASK + s) * 32 + q32] = l;
    }
}

// ---------------- kernel 3: merge per-chunk partials, divide by l
__global__ __launch_bounds__(256) void attn_merge(const unsigned short* __restrict__ Opart,
                                                  const float* __restrict__ Mpart,
                                                  const float* __restrict__ Lpart,
                                                  float* __restrict__ out) {
    int tid = threadIdx.x;
    int g = blockIdx.x * 64 + (tid >> 2);   // global row
    int h0 = (tid & 3) * 16;
    int b = g >> 12, t = g & 4095;
    int tile = t >> 5, r32 = t & 31;
    int k = tile >> 4;
    int nch = k + 1;
    int s0 = 16 * (36 - (((k + 1) * (k + 2)) >> 1)) + (15 - (tile & 15)) * nch;
    int tb = b * NTASK + s0;

    float mm = -3e38f;
    for (int i = 0; i < nch; i++) mm = fmaxf(mm, Mpart[(tb + i) * 32 + r32]);
    float ll = 0.f;
    float acc[16];
#pragma unroll
    for (int e = 0; e < 16; e++) acc[e] = 0.f;
    for (int i = 0; i < nch; i++) {
        float a = exp2f(Mpart[(tb + i) * 32 + r32] - mm);
        ll += a * Lpart[(tb + i) * 32 + r32];
        const unsigned short* op = Opart + ((size_t)(tb + i) * 32 + r32) * 64 + h0;
        short8 v0 = *(const short8*)op;
        short8 v1 = *(const short8*)(op + 8);
#pragma unroll
        for (int e = 0; e < 8; e++) {
            acc[e]     += a * bf16_to_f32((unsigned short)v0[e]);
            acc[8 + e] += a * bf16_to_f32((unsigned short)v1[e]);
        }
    }
    float inv = 1.f / ll;
    float* dst = out + (size_t)g * 64 + h0;
#pragma unroll
    for (int e = 0; e < 16; e++) dst[e] = acc[e] * inv;
}

extern "C" void kernel_launch(void* const* d_in, const int* in_sizes, int n_in,
                              void* d_out, int out_size, void* d_ws, size_t ws_size,
                              hipStream_t stream) {
    (void)in_sizes; (void)n_in; (void)out_size; (void)ws_size;
    const float* x  = (const float*)d_in[0];
    const float* Wk = (const float*)d_in[1];
    const float* Wq = (const float*)d_in[2];
    const float* Wv = (const float*)d_in[3];
    float* out = (float*)d_out;

    unsigned short* Wb = (unsigned short*)d_ws;              // 192*1024
    unsigned short* Kb = Wb + 196608;                        // 16384*64
    unsigned short* Qb = Kb + 1048576;                       // pre-scaled by QSCALE
    unsigned short* Vt = Qb + 1048576;                       // (b, 64, t)
    unsigned short* Opart = Vt + 1048576;                    // [4*576][32][64] bf16
    float* Mpart = (float*)(Opart + (size_t)4 * NTASK * 32 * 64);
    float* Lpart = Mpart + 4 * NTASK * 32;

    hipLaunchKernelGGL(convert_w, dim3(96), dim3(256), 0, stream, Wk, Wq, Wv, Wb);
    hipLaunchKernelGGL(qkv_proj, dim3(512), dim3(256), 0, stream, x, Wb, Kb, Qb, Vt);
    hipLaunchKernelGGL(attn, dim3(NTASK, 4), dim3(64), 0, stream, Qb, Kb, Vt, Opart, Mpart, Lpart);
    hipLaunchKernelGGL(attn_merge, dim3(256), dim3(256), 0, stream, Opart, Mpart, Lpart, out);
}

// Round 6
// 87.409 us; speedup vs baseline: 2.8989x; 1.2444x over previous
//
#include <hip/hip_runtime.h>
#include <hip/hip_bf16.h>

#define D_EMB 1024
#define T_LEN 4096
#define NTASK 576  // attn tasks per batch (sum of ceil((t+1)/16), t=0..127)

typedef short short8 __attribute__((ext_vector_type(8)));
typedef float f32x4 __attribute__((ext_vector_type(4)));
typedef float f32x16 __attribute__((ext_vector_type(16)));
typedef float float4v __attribute__((ext_vector_type(4)));

__device__ __forceinline__ unsigned short f32_to_bf16(float f) {
    union { float f; unsigned int u; } c; c.f = f;
    unsigned int u = c.u;
    return (unsigned short)((u + 0x7FFFu + ((u >> 16) & 1u)) >> 16);
}
__device__ __forceinline__ float bf16_to_f32(unsigned short v) {
    union { unsigned int u; float f; } c; c.u = ((unsigned int)v) << 16;
    return c.f;
}
__device__ __forceinline__ unsigned cvtpk_bf16(float a, float b) {
    unsigned r;
    asm("v_cvt_pk_bf16_f32 %0, %1, %2" : "=v"(r) : "v"(a), "v"(b));
    return r;
}
__device__ __forceinline__ void gl_lds16(const void* g, void* l) {
    __builtin_amdgcn_global_load_lds(
        (const __attribute__((address_space(1))) unsigned int*)(g),
        (__attribute__((address_space(3))) unsigned int*)(l), 16, 0, 0);
}

// scale folded into Q: 1/sqrt(64) * log2(e)  (softmax done in exp2 domain)
#define QSCALE (0.125f * 1.44269504f)

// ---------------- kernel 0: convert W -> bf16, XOR-swizzled within 64-col blocks
// dst element index = e ^ ((row&7)<<3), row = e>>10. (8-elem groups permuted;
// staging a 64-col k-slice linearly into LDS then reading with the same XOR
// gives bank-balanced ds_read_b128.)
__global__ __launch_bounds__(256) void convert_w(const float* __restrict__ Wk,
                                                 const float* __restrict__ Wq,
                                                 const float* __restrict__ Wv,
                                                 unsigned short* __restrict__ Wb) {
    int e = (blockIdx.x * 256 + threadIdx.x) * 8;
    const float* src;
    if (e < 65536) src = Wk + e;
    else if (e < 131072) src = Wq + (e - 65536);
    else src = Wv + (e - 131072);
    float4v a0 = *(const float4v*)src;
    float4v a1 = *(const float4v*)(src + 4);
    short8 r;
    r[0] = (short)f32_to_bf16(a0[0]); r[1] = (short)f32_to_bf16(a0[1]);
    r[2] = (short)f32_to_bf16(a0[2]); r[3] = (short)f32_to_bf16(a0[3]);
    r[4] = (short)f32_to_bf16(a1[0]); r[5] = (short)f32_to_bf16(a1[1]);
    r[6] = (short)f32_to_bf16(a1[2]); r[7] = (short)f32_to_bf16(a1[3]);
    int row = e >> 10;
    int dst = e ^ ((row & 7) << 3);
    *(short8*)(Wb + dst) = r;
}

// ---------------- kernel 1: QKV projection, LDS-staged GEMM
// Grid 512, block 256 (4 waves). BM=32 rows; wave (rg, nh): rows rg*16..+15,
// out-cols nh*96..+95. Per BK=64 step: stage next W-slice [192][64] (24 KB,
// dbuf) via global_load_lds; A from global fp32 + cvt_pk; 12 ds_read_b128 +
// 12 MFMA per wave. Staging decode: lane carries 16B=8 elems -> 8 lanes/row:
// row = u>>3, koff = (u&7)*8 (u = unit*64+lane).
__global__ __launch_bounds__(256, 2) void qkv_proj(const float* __restrict__ x,
                                                   const unsigned short* __restrict__ Wb,
                                                   unsigned short* __restrict__ Kb,
                                                   unsigned short* __restrict__ Qb,
                                                   unsigned short* __restrict__ Vt) {
    __shared__ __attribute__((aligned(16))) unsigned short Wsl[2][12288];  // [192][64] bf16

    int tid = threadIdx.x;
    int lane = tid & 63, wave = tid >> 6;
    int lo = lane & 15, hi = lane >> 4;
    int rg = wave >> 1, nh = wave & 1;
    int row0 = blockIdx.x * 32;

    const float* xp = x + (size_t)(row0 + rg * 16 + lo) * D_EMB;

    f32x4 acc[6];
#pragma unroll
    for (int i = 0; i < 6; i++) acc[i] = (f32x4){0.f, 0.f, 0.f, 0.f};

    // stage slice 0
#pragma unroll
    for (int j = 0; j < 6; j++) {
        int unit = j * 4 + wave;
        int u = unit * 64 + lane;
        gl_lds16(Wb + (size_t)(u >> 3) * D_EMB + (u & 7) * 8, &Wsl[0][unit * 512]);
    }
    __syncthreads();

    int buf = 0;
    int xorm = (lo & 7) << 4;
    int rowbase = nh * 96 + lo;  // n*16+lo = rowbase + i*16

    for (int kt = 0; kt < 16; kt++) {
        if (kt < 15) {
            int k0n = (kt + 1) * 64;
#pragma unroll
            for (int j = 0; j < 6; j++) {
                int unit = j * 4 + wave;
                int u = unit * 64 + lane;
                gl_lds16(Wb + (size_t)(u >> 3) * D_EMB + k0n + (u & 7) * 8,
                         &Wsl[buf ^ 1][unit * 512]);
            }
        }
        // A fragments: x rows, k = kt*64 + ks*32 + hi*8 .. +7
        short8 af[2];
#pragma unroll
        for (int ks = 0; ks < 2; ks++) {
            const float* p = xp + kt * 64 + ks * 32 + hi * 8;
            float4v a0 = *(const float4v*)p;
            float4v a1 = *(const float4v*)(p + 4);
            union { unsigned u[4]; short8 s; } c;
            c.u[0] = cvtpk_bf16(a0[0], a0[1]);
            c.u[1] = cvtpk_bf16(a0[2], a0[3]);
            c.u[2] = cvtpk_bf16(a1[0], a1[1]);
            c.u[3] = cvtpk_bf16(a1[2], a1[3]);
            af[ks] = c.s;
        }
        const char* sb = (const char*)&Wsl[buf][0];
#pragma unroll
        for (int i = 0; i < 6; i++) {
            int row = rowbase + i * 16;
#pragma unroll
            for (int ks = 0; ks < 2; ks++) {
                short8 bfrag = *(const short8*)(sb + row * 128 + ((ks * 64 + hi * 16) ^ xorm));
                acc[i] = __builtin_amdgcn_mfma_f32_16x16x32_bf16(af[ks], bfrag, acc[i], 0, 0, 0);
            }
        }
        __syncthreads();
        buf ^= 1;
    }

    // epilogue: acc[i][r] -> row = row0+rg*16+hi*4+r, col = nh*96+i*16+lo
#pragma unroll
    for (int i = 0; i < 6; i++) {
        int n = nh * 6 + i;
#pragma unroll
        for (int r = 0; r < 4; r++) {
            int grow = row0 + rg * 16 + hi * 4 + r;
            float val = acc[i][r];
            if (n < 4) {
                Kb[(size_t)grow * 64 + n * 16 + lo] = f32_to_bf16(val);
            } else if (n < 8) {
                Qb[(size_t)grow * 64 + (n - 4) * 16 + lo] = f32_to_bf16(val * QSCALE);
            } else {
                int bb = grow >> 12;
                Vt[((size_t)bb * 64 + (n - 8) * 16 + lo) * T_LEN + (grow & 4095)] = f32_to_bf16(val);
            }
        }
    }
}

// ---------------- kernel 2: causal flash attention, 1 wave per task.
// Task = (tile of 32 q-rows, chunk of <=512 keys). Swapped QK^T via 32x32x16
// MFMA: S^T col = q = lane&31 (lane-local softmax state). PV accumulates O^T.
// No LDS, no barriers. Partials (m, l, O) out; merged by attn_merge.
__global__ __launch_bounds__(64, 3) void attn(const unsigned short* __restrict__ Qb,
                                              const unsigned short* __restrict__ Kb,
                                              const unsigned short* __restrict__ Vt,
                                              unsigned short* __restrict__ Opart,
                                              float* __restrict__ Mpart,
                                              float* __restrict__ Lpart) {
    int lane = threadIdx.x;
    int q32 = lane & 31;
    int hi = lane >> 5;
    int s = blockIdx.x;   // 0..575, heavy tiles first
    int b = blockIdx.y;

    // decode (tile t, chunk c): group k has tiles [16k,16k+15], k+1 chunks each
    int k = 7, rem = s;
    while (rem >= 16 * (k + 1)) { rem -= 16 * (k + 1); k--; }
    int cpt = k + 1;
    int ti = rem / cpt;
    int t = (k << 4) + 15 - ti;
    int c = rem - ti * cpt;

    int u0 = c * 16;
    int u1 = min(u0 + 16, t + 1);   // 32-key units

    size_t base = (size_t)b * T_LEN;
    int q0 = t * 32;
    int qg = q0 + q32;

    // Q B-fragments (col=q=lane&31, k-rows d = 16*ds + 8*hi + j)
    short8 qf[4];
    const unsigned short* qp = Qb + (base + qg) * 64 + hi * 8;
#pragma unroll
    for (int d = 0; d < 4; d++) qf[d] = *(const short8*)(qp + d * 16);

    size_t vbase = ((size_t)b * 64 + q32) * T_LEN;
    f32x16 o0 = {0.f}, o1 = {0.f};
    float m = -3e38f, l = 0.f;

    for (int u = u0; u < u1; ++u) {
        int kv0 = u * 32;
        const unsigned short* kp = Kb + (base + kv0 + q32) * 64 + hi * 8;
        short8 kf0 = *(const short8*)kp;
        short8 kf1 = *(const short8*)(kp + 16);
        short8 kf2 = *(const short8*)(kp + 32);
        short8 kf3 = *(const short8*)(kp + 48);
        const unsigned short* vp = Vt + vbase + kv0 + hi * 8;
        short8 vf00 = *(const short8*)vp;
        short8 vf01 = *(const short8*)(vp + 16);
        short8 vf10 = *(const short8*)(vp + 32 * T_LEN);
        short8 vf11 = *(const short8*)(vp + 32 * T_LEN + 16);

        // S^T = K * Q^T : col = q (lane&31), row k = (r&3)+8*(r>>2)+4*hi
        f32x16 sc = {0.f};
        sc = __builtin_amdgcn_mfma_f32_32x32x16_bf16(kf0, qf[0], sc, 0, 0, 0);
        sc = __builtin_amdgcn_mfma_f32_32x32x16_bf16(kf1, qf[1], sc, 0, 0, 0);
        sc = __builtin_amdgcn_mfma_f32_32x32x16_bf16(kf2, qf[2], sc, 0, 0, 0);
        sc = __builtin_amdgcn_mfma_f32_32x32x16_bf16(kf3, qf[3], sc, 0, 0, 0);

        if (u == t) {  // diagonal unit: causal mask
#pragma unroll
            for (int r = 0; r < 16; ++r) {
                int ko = (r & 3) + 8 * (r >> 2) + 4 * hi;
                sc[r] = (ko <= q32) ? sc[r] : -3e38f;
            }
        }

        // row max: tree over 16 regs + one cross-half exchange
        float x0 = fmaxf(sc[0], sc[8]),  x1 = fmaxf(sc[1], sc[9]);
        float x2 = fmaxf(sc[2], sc[10]), x3 = fmaxf(sc[3], sc[11]);
        float x4 = fmaxf(sc[4], sc[12]), x5 = fmaxf(sc[5], sc[13]);
        float x6 = fmaxf(sc[6], sc[14]), x7 = fmaxf(sc[7], sc[15]);
        x0 = fmaxf(x0, x4); x1 = fmaxf(x1, x5); x2 = fmaxf(x2, x6); x3 = fmaxf(x3, x7);
        x0 = fmaxf(x0, x2); x1 = fmaxf(x1, x3);
        float mx = fmaxf(x0, x1);
        mx = fmaxf(mx, __shfl_xor(mx, 32));

        // defer-max (THR=8): skip O-rescale when max barely grew
        if (__any(mx > m + 8.0f)) {
            float mn = fmaxf(m, mx);
            float al = exp2f(m - mn);
            m = mn; l *= al;
#pragma unroll
            for (int r = 0; r < 16; ++r) { o0[r] *= al; o1[r] *= al; }
        }

#pragma unroll
        for (int r = 0; r < 16; ++r) sc[r] = exp2f(sc[r] - m);
        float y0 = (sc[0] + sc[8]) + (sc[4] + sc[12]);
        float y1 = (sc[1] + sc[9]) + (sc[5] + sc[13]);
        float y2 = (sc[2] + sc[10]) + (sc[6] + sc[14]);
        float y3 = (sc[3] + sc[11]) + (sc[7] + sc[15]);
        float sum = (y0 + y1) + (y2 + y3);
        sum += __shfl_xor(sum, 32);
        l += sum;

        // pack P -> bf16 PV B-fragments (cvt_pk + permlane32_swap, guide T12)
        unsigned bb0, bb1, bb2, bb3, bb4, bb5, bb6, bb7;
        asm("v_cvt_pk_bf16_f32 %0, %1, %2" : "=v"(bb0) : "v"(sc[0]),  "v"(sc[1]));
        asm("v_cvt_pk_bf16_f32 %0, %1, %2" : "=v"(bb1) : "v"(sc[2]),  "v"(sc[3]));
        asm("v_cvt_pk_bf16_f32 %0, %1, %2" : "=v"(bb2) : "v"(sc[4]),  "v"(sc[5]));
        asm("v_cvt_pk_bf16_f32 %0, %1, %2" : "=v"(bb3) : "v"(sc[6]),  "v"(sc[7]));
        asm("v_cvt_pk_bf16_f32 %0, %1, %2" : "=v"(bb4) : "v"(sc[8]),  "v"(sc[9]));
        asm("v_cvt_pk_bf16_f32 %0, %1, %2" : "=v"(bb5) : "v"(sc[10]), "v"(sc[11]));
        asm("v_cvt_pk_bf16_f32 %0, %1, %2" : "=v"(bb6) : "v"(sc[12]), "v"(sc[13]));
        asm("v_cvt_pk_bf16_f32 %0, %1, %2" : "=v"(bb7) : "v"(sc[14]), "v"(sc[15]));
        asm("v_permlane32_swap_b32 %0, %1" : "+v"(bb0), "+v"(bb2));
        asm("v_permlane32_swap_b32 %0, %1" : "+v"(bb1), "+v"(bb3));
        asm("v_permlane32_swap_b32 %0, %1" : "+v"(bb4), "+v"(bb6));
        asm("v_permlane32_swap_b32 %0, %1" : "+v"(bb5), "+v"(bb7));
        union U8 { unsigned u[4]; short8 s; };
        U8 p0; p0.u[0] = bb0; p0.u[1] = bb1; p0.u[2] = bb2; p0.u[3] = bb3;
        U8 p1; p1.u[0] = bb4; p1.u[1] = bb5; p1.u[2] = bb6; p1.u[3] = bb7;

        // O^T += V^T * P^T  (col = q, rows = h)
        o0 = __builtin_amdgcn_mfma_f32_32x32x16_bf16(vf00, p0.s, o0, 0, 0, 0);
        o0 = __builtin_amdgcn_mfma_f32_32x32x16_bf16(vf01, p1.s, o0, 0, 0, 0);
        o1 = __builtin_amdgcn_mfma_f32_32x32x16_bf16(vf10, p0.s, o1, 0, 0, 0);
        o1 = __builtin_amdgcn_mfma_f32_32x32x16_bf16(vf11, p1.s, o1, 0, 0, 0);
    }

    // store partial: Opart[(b*NTASK+s)][q32][h] bf16
    size_t tbase = ((size_t)(b * NTASK + s) * 32 + q32) * 64;
#pragma unroll
    for (int hb = 0; hb < 2; hb++) {
#pragma unroll
        for (int g = 0; g < 4; g++) {
            float e0 = hb ? o1[4 * g] : o0[4 * g];
            float e1 = hb ? o1[4 * g + 1] : o0[4 * g + 1];
            float e2 = hb ? o1[4 * g + 2] : o0[4 * g + 2];
            float e3 = hb ? o1[4 * g + 3] : o0[4 * g + 3];
            unsigned w0, w1;
            asm("v_cvt_pk_bf16_f32 %0, %1, %2" : "=v"(w0) : "v"(e0), "v"(e1));
            asm("v_cvt_pk_bf16_f32 %0, %1, %2" : "=v"(w1) : "v"(e2), "v"(e3));
            int h0 = hb * 32 + g * 8 + hi * 4;
            *reinterpret_cast<uint2*>(Opart + tbase + h0) = make_uint2(w0, w1);
        }
    }
    if (lane < 32) {
        Mpart[(b * NTASK + s) * 32 + q32] = m;
        Lpart[(b * NTASK + s) * 32 + q32] = l;
    }
}

// ---------------- kernel 3: merge per-chunk partials, divide by l
__global__ __launch_bounds__(256) void attn_merge(const unsigned short* __restrict__ Opart,
                                                  const float* __restrict__ Mpart,
                                                  const float* __restrict__ Lpart,
                                                  float* __restrict__ out) {
    int tid = threadIdx.x;
    int g = blockIdx.x * 64 + (tid >> 2);   // global row
    int h0 = (tid & 3) * 16;
    int b = g >> 12, t = g & 4095;
    int tile = t >> 5, r32 = t & 31;
    int k = tile >> 4;
    int nch = k + 1;
    int s0 = 16 * (36 - (((k + 1) * (k + 2)) >> 1)) + (15 - (tile & 15)) * nch;
    int tb = b * NTASK + s0;

    float mm = -3e38f;
    for (int i = 0; i < nch; i++) mm = fmaxf(mm, Mpart[(tb + i) * 32 + r32]);
    float ll = 0.f;
    float acc[16];
#pragma unroll
    for (int e = 0; e < 16; e++) acc[e] = 0.f;
    for (int i = 0; i < nch; i++) {
        float a = exp2f(Mpart[(tb + i) * 32 + r32] - mm);
        ll += a * Lpart[(tb + i) * 32 + r32];
        const unsigned short* op = Opart + ((size_t)(tb + i) * 32 + r32) * 64 + h0;
        short8 v0 = *(const short8*)op;
        short8 v1 = *(const short8*)(op + 8);
#pragma unroll
        for (int e = 0; e < 8; e++) {
            acc[e]     += a * bf16_to_f32((unsigned short)v0[e]);
            acc[8 + e] += a * bf16_to_f32((unsigned short)v1[e]);
        }
    }
    float inv = 1.f / ll;
    float* dst = out + (size_t)g * 64 + h0;
#pragma unroll
    for (int e = 0; e < 16; e++) dst[e] = acc[e] * inv;
}

extern "C" void kernel_launch(void* const* d_in, const int* in_sizes, int n_in,
                              void* d_out, int out_size, void* d_ws, size_t ws_size,
                              hipStream_t stream) {
    (void)in_sizes; (void)n_in; (void)out_size; (void)ws_size;
    const float* x  = (const float*)d_in[0];
    const float* Wk = (const float*)d_in[1];
    const float* Wq = (const float*)d_in[2];
    const float* Wv = (const float*)d_in[3];
    float* out = (float*)d_out;

    unsigned short* Wb = (unsigned short*)d_ws;              // 192*1024 (swizzled)
    unsigned short* Kb = Wb + 196608;                        // 16384*64
    unsigned short* Qb = Kb + 1048576;                       // pre-scaled by QSCALE
    unsigned short* Vt = Qb + 1048576;                       // (b, 64, t)
    unsigned short* Opart = Vt + 1048576;                    // [4*576][32][64] bf16
    float* Mpart = (float*)(Opart + (size_t)4 * NTASK * 32 * 64);
    float* Lpart = Mpart + 4 * NTASK * 32;

    hipLaunchKernelGGL(convert_w, dim3(96), dim3(256), 0, stream, Wk, Wq, Wv, Wb);
    hipLaunchKernelGGL(qkv_proj, dim3(512), dim3(256), 0, stream, x, Wb, Kb, Qb, Vt);
    hipLaunchKernelGGL(attn, dim3(NTASK, 4), dim3(64), 0, stream, Qb, Kb, Vt, Opart, Mpart, Lpart);
    hipLaunchKernelGGL(attn_merge, dim3(256), dim3(256), 0, stream, Opart, Mpart, Lpart, out);
}

// Round 7
// 83.801 us; speedup vs baseline: 3.0237x; 1.0431x over previous
//
#include <hip/hip_runtime.h>
#include <hip/hip_bf16.h>

#define D_EMB 1024
#define T_LEN 4096
#define NTASK 576  // attn tasks per batch (sum of ceil((t+1)/16), t=0..127)

typedef short short8 __attribute__((ext_vector_type(8)));
typedef float f32x4 __attribute__((ext_vector_type(4)));
typedef float f32x16 __attribute__((ext_vector_type(16)));
typedef float float4v __attribute__((ext_vector_type(4)));

__device__ __forceinline__ unsigned short f32_to_bf16(float f) {
    union { float f; unsigned int u; } c; c.f = f;
    unsigned int u = c.u;
    return (unsigned short)((u + 0x7FFFu + ((u >> 16) & 1u)) >> 16);
}
__device__ __forceinline__ float bf16_to_f32(unsigned short v) {
    union { unsigned int u; float f; } c; c.u = ((unsigned int)v) << 16;
    return c.f;
}
__device__ __forceinline__ unsigned cvtpk_bf16(float a, float b) {
    unsigned r;
    asm("v_cvt_pk_bf16_f32 %0, %1, %2" : "=v"(r) : "v"(a), "v"(b));
    return r;
}
__device__ __forceinline__ void gl_lds16(const void* g, void* l) {
    __builtin_amdgcn_global_load_lds(
        (const __attribute__((address_space(1))) unsigned int*)(g),
        (__attribute__((address_space(3))) unsigned int*)(l), 16, 0, 0);
}

// scale folded into Q: 1/sqrt(64) * log2(e)  (softmax done in exp2 domain)
#define QSCALE (0.125f * 1.44269504f)

// ---------------- kernel 0: convert W -> bf16, XOR-swizzled within 64-col blocks
__global__ __launch_bounds__(256) void convert_w(const float* __restrict__ Wk,
                                                 const float* __restrict__ Wq,
                                                 const float* __restrict__ Wv,
                                                 unsigned short* __restrict__ Wb) {
    int e = (blockIdx.x * 256 + threadIdx.x) * 8;
    const float* src;
    if (e < 65536) src = Wk + e;
    else if (e < 131072) src = Wq + (e - 65536);
    else src = Wv + (e - 131072);
    float4v a0 = *(const float4v*)src;
    float4v a1 = *(const float4v*)(src + 4);
    short8 r;
    r[0] = (short)f32_to_bf16(a0[0]); r[1] = (short)f32_to_bf16(a0[1]);
    r[2] = (short)f32_to_bf16(a0[2]); r[3] = (short)f32_to_bf16(a0[3]);
    r[4] = (short)f32_to_bf16(a1[0]); r[5] = (short)f32_to_bf16(a1[1]);
    r[6] = (short)f32_to_bf16(a1[2]); r[7] = (short)f32_to_bf16(a1[3]);
    int row = e >> 10;
    int dst = e ^ ((row & 7) << 3);
    *(short8*)(Wb + dst) = r;
}

// ---------------- kernel 1: QKV projection, LDS-staged GEMM + x reg-prefetch
// Grid 512, block 256 (4 waves). Per BK=64 step: issue x loads for kt+1 FIRST
// (T14 issue-early/consume-late), stage next W-slice via global_load_lds (dbuf),
// then cvt(current x) + 12 ds_read_b128 + 12 MFMA; one barrier per step.
__global__ __launch_bounds__(256, 2) void qkv_proj(const float* __restrict__ x,
                                                   const unsigned short* __restrict__ Wb,
                                                   unsigned short* __restrict__ Kb,
                                                   unsigned short* __restrict__ Qb,
                                                   unsigned short* __restrict__ Vt) {
    __shared__ __attribute__((aligned(16))) unsigned short Wsl[2][12288];  // [192][64] bf16

    int tid = threadIdx.x;
    int lane = tid & 63, wave = tid >> 6;
    int lo = lane & 15, hi = lane >> 4;
    int rg = wave >> 1, nh = wave & 1;
    int row0 = blockIdx.x * 32;

    const float* xp = x + (size_t)(row0 + rg * 16 + lo) * D_EMB + hi * 8;

    f32x4 acc[6];
#pragma unroll
    for (int i = 0; i < 6; i++) acc[i] = (f32x4){0.f, 0.f, 0.f, 0.f};

    // issue x loads for kt=0
    float4v xa0 = *(const float4v*)(xp);
    float4v xa1 = *(const float4v*)(xp + 4);
    float4v xa2 = *(const float4v*)(xp + 32);
    float4v xa3 = *(const float4v*)(xp + 36);

    // stage W slice 0
#pragma unroll
    for (int j = 0; j < 6; j++) {
        int unit = j * 4 + wave;
        int u = unit * 64 + lane;
        gl_lds16(Wb + (size_t)(u >> 3) * D_EMB + (u & 7) * 8, &Wsl[0][unit * 512]);
    }
    __syncthreads();

    int buf = 0;
    int xorm = (lo & 7) << 4;
    int rowbase = nh * 96 + lo;

    for (int kt = 0; kt < 16; kt++) {
        // prefetch x for kt+1 (clamped; issued before everything else)
        int ktn = (kt < 15) ? kt + 1 : 15;
        const float* pn = xp + ktn * 64;
        float4v xn0 = *(const float4v*)(pn);
        float4v xn1 = *(const float4v*)(pn + 4);
        float4v xn2 = *(const float4v*)(pn + 32);
        float4v xn3 = *(const float4v*)(pn + 36);

        // stage W slice kt+1
        if (kt < 15) {
            int k0n = (kt + 1) * 64;
#pragma unroll
            for (int j = 0; j < 6; j++) {
                int unit = j * 4 + wave;
                int u = unit * 64 + lane;
                gl_lds16(Wb + (size_t)(u >> 3) * D_EMB + k0n + (u & 7) * 8,
                         &Wsl[buf ^ 1][unit * 512]);
            }
        }

        // cvt current x -> A fragments
        short8 af[2];
        {
            union { unsigned u[4]; short8 s; } c;
            c.u[0] = cvtpk_bf16(xa0[0], xa0[1]);
            c.u[1] = cvtpk_bf16(xa0[2], xa0[3]);
            c.u[2] = cvtpk_bf16(xa1[0], xa1[1]);
            c.u[3] = cvtpk_bf16(xa1[2], xa1[3]);
            af[0] = c.s;
            c.u[0] = cvtpk_bf16(xa2[0], xa2[1]);
            c.u[1] = cvtpk_bf16(xa2[2], xa2[3]);
            c.u[2] = cvtpk_bf16(xa3[0], xa3[1]);
            c.u[3] = cvtpk_bf16(xa3[2], xa3[3]);
            af[1] = c.s;
        }

        const char* sb = (const char*)&Wsl[buf][0];
#pragma unroll
        for (int i = 0; i < 6; i++) {
            int row = rowbase + i * 16;
#pragma unroll
            for (int ks = 0; ks < 2; ks++) {
                short8 bfrag = *(const short8*)(sb + row * 128 + ((ks * 64 + hi * 16) ^ xorm));
                acc[i] = __builtin_amdgcn_mfma_f32_16x16x32_bf16(af[ks], bfrag, acc[i], 0, 0, 0);
            }
        }
        __syncthreads();
        buf ^= 1;
        xa0 = xn0; xa1 = xn1; xa2 = xn2; xa3 = xn3;
    }

    // epilogue
#pragma unroll
    for (int i = 0; i < 6; i++) {
        int n = nh * 6 + i;
#pragma unroll
        for (int r = 0; r < 4; r++) {
            int grow = row0 + rg * 16 + hi * 4 + r;
            float val = acc[i][r];
            if (n < 4) {
                Kb[(size_t)grow * 64 + n * 16 + lo] = f32_to_bf16(val);
            } else if (n < 8) {
                Qb[(size_t)grow * 64 + (n - 4) * 16 + lo] = f32_to_bf16(val * QSCALE);
            } else {
                int bb = grow >> 12;
                Vt[((size_t)bb * 64 + (n - 8) * 16 + lo) * T_LEN + (grow & 4095)] = f32_to_bf16(val);
            }
        }
    }
}

// ---------------- kernel 2: causal flash attention, 1 wave per task, K/V prefetch.
__global__ __launch_bounds__(64, 3) void attn(const unsigned short* __restrict__ Qb,
                                              const unsigned short* __restrict__ Kb,
                                              const unsigned short* __restrict__ Vt,
                                              unsigned short* __restrict__ Opart,
                                              float* __restrict__ Mpart,
                                              float* __restrict__ Lpart) {
    int lane = threadIdx.x;
    int q32 = lane & 31;
    int hi = lane >> 5;
    int s = blockIdx.x;   // 0..575, heavy tiles first
    int b = blockIdx.y;

    // decode (tile t, chunk c): group k has tiles [16k,16k+15], k+1 chunks each
    int k = 7, rem = s;
    while (rem >= 16 * (k + 1)) { rem -= 16 * (k + 1); k--; }
    int cpt = k + 1;
    int ti = rem / cpt;
    int t = (k << 4) + 15 - ti;
    int c = rem - ti * cpt;

    int u0 = c * 16;
    int u1 = min(u0 + 16, t + 1);   // 32-key units

    size_t base = (size_t)b * T_LEN;
    int q0 = t * 32;
    int qg = q0 + q32;

    // Q B-fragments
    short8 qf[4];
    const unsigned short* qp = Qb + (base + qg) * 64 + hi * 8;
#pragma unroll
    for (int d = 0; d < 4; d++) qf[d] = *(const short8*)(qp + d * 16);

    size_t vbase = ((size_t)b * 64 + q32) * T_LEN;
    f32x16 o0 = {0.f}, o1 = {0.f};
    float m = -3e38f, l = 0.f;

    // preload K/V for u0
    short8 kc0, kc1, kc2, kc3, vc0, vc1, vc2, vc3;
    {
        const unsigned short* kp = Kb + (base + u0 * 32 + q32) * 64 + hi * 8;
        kc0 = *(const short8*)kp;
        kc1 = *(const short8*)(kp + 16);
        kc2 = *(const short8*)(kp + 32);
        kc3 = *(const short8*)(kp + 48);
        const unsigned short* vp = Vt + vbase + u0 * 32 + hi * 8;
        vc0 = *(const short8*)vp;
        vc1 = *(const short8*)(vp + 16);
        vc2 = *(const short8*)(vp + 32 * T_LEN);
        vc3 = *(const short8*)(vp + 32 * T_LEN + 16);
    }

    for (int u = u0; u < u1; ++u) {
        // prefetch next unit (clamped -> redundant L2 hit on last iter)
        int un = (u + 1 < u1) ? u + 1 : u;
        const unsigned short* kpn = Kb + (base + un * 32 + q32) * 64 + hi * 8;
        short8 kn0 = *(const short8*)kpn;
        short8 kn1 = *(const short8*)(kpn + 16);
        short8 kn2 = *(const short8*)(kpn + 32);
        short8 kn3 = *(const short8*)(kpn + 48);
        const unsigned short* vpn = Vt + vbase + un * 32 + hi * 8;
        short8 vn0 = *(const short8*)vpn;
        short8 vn1 = *(const short8*)(vpn + 16);
        short8 vn2 = *(const short8*)(vpn + 32 * T_LEN);
        short8 vn3 = *(const short8*)(vpn + 32 * T_LEN + 16);

        // S^T = K * Q^T : col = q (lane&31), row k = (r&3)+8*(r>>2)+4*hi
        f32x16 sc = {0.f};
        sc = __builtin_amdgcn_mfma_f32_32x32x16_bf16(kc0, qf[0], sc, 0, 0, 0);
        sc = __builtin_amdgcn_mfma_f32_32x32x16_bf16(kc1, qf[1], sc, 0, 0, 0);
        sc = __builtin_amdgcn_mfma_f32_32x32x16_bf16(kc2, qf[2], sc, 0, 0, 0);
        sc = __builtin_amdgcn_mfma_f32_32x32x16_bf16(kc3, qf[3], sc, 0, 0, 0);

        if (u == t) {  // diagonal unit: causal mask
#pragma unroll
            for (int r = 0; r < 16; ++r) {
                int ko = (r & 3) + 8 * (r >> 2) + 4 * hi;
                sc[r] = (ko <= q32) ? sc[r] : -3e38f;
            }
        }

        // row max: tree over 16 regs + one cross-half exchange
        float x0 = fmaxf(sc[0], sc[8]),  x1 = fmaxf(sc[1], sc[9]);
        float x2 = fmaxf(sc[2], sc[10]), x3 = fmaxf(sc[3], sc[11]);
        float x4 = fmaxf(sc[4], sc[12]), x5 = fmaxf(sc[5], sc[13]);
        float x6 = fmaxf(sc[6], sc[14]), x7 = fmaxf(sc[7], sc[15]);
        x0 = fmaxf(x0, x4); x1 = fmaxf(x1, x5); x2 = fmaxf(x2, x6); x3 = fmaxf(x3, x7);
        x0 = fmaxf(x0, x2); x1 = fmaxf(x1, x3);
        float mx = fmaxf(x0, x1);
        mx = fmaxf(mx, __shfl_xor(mx, 32));

        // defer-max (THR=8)
        if (__any(mx > m + 8.0f)) {
            float mn = fmaxf(m, mx);
            float al = exp2f(m - mn);
            m = mn; l *= al;
#pragma unroll
            for (int r = 0; r < 16; ++r) { o0[r] *= al; o1[r] *= al; }
        }

#pragma unroll
        for (int r = 0; r < 16; ++r) sc[r] = exp2f(sc[r] - m);
        float y0 = (sc[0] + sc[8]) + (sc[4] + sc[12]);
        float y1 = (sc[1] + sc[9]) + (sc[5] + sc[13]);
        float y2 = (sc[2] + sc[10]) + (sc[6] + sc[14]);
        float y3 = (sc[3] + sc[11]) + (sc[7] + sc[15]);
        float sum = (y0 + y1) + (y2 + y3);
        sum += __shfl_xor(sum, 32);
        l += sum;

        // pack P -> bf16 PV B-fragments (cvt_pk + permlane32_swap, guide T12)
        unsigned bb0, bb1, bb2, bb3, bb4, bb5, bb6, bb7;
        asm("v_cvt_pk_bf16_f32 %0, %1, %2" : "=v"(bb0) : "v"(sc[0]),  "v"(sc[1]));
        asm("v_cvt_pk_bf16_f32 %0, %1, %2" : "=v"(bb1) : "v"(sc[2]),  "v"(sc[3]));
        asm("v_cvt_pk_bf16_f32 %0, %1, %2" : "=v"(bb2) : "v"(sc[4]),  "v"(sc[5]));
        asm("v_cvt_pk_bf16_f32 %0, %1, %2" : "=v"(bb3) : "v"(sc[6]),  "v"(sc[7]));
        asm("v_cvt_pk_bf16_f32 %0, %1, %2" : "=v"(bb4) : "v"(sc[8]),  "v"(sc[9]));
        asm("v_cvt_pk_bf16_f32 %0, %1, %2" : "=v"(bb5) : "v"(sc[10]), "v"(sc[11]));
        asm("v_cvt_pk_bf16_f32 %0, %1, %2" : "=v"(bb6) : "v"(sc[12]), "v"(sc[13]));
        asm("v_cvt_pk_bf16_f32 %0, %1, %2" : "=v"(bb7) : "v"(sc[14]), "v"(sc[15]));
        asm("v_permlane32_swap_b32 %0, %1" : "+v"(bb0), "+v"(bb2));
        asm("v_permlane32_swap_b32 %0, %1" : "+v"(bb1), "+v"(bb3));
        asm("v_permlane32_swap_b32 %0, %1" : "+v"(bb4), "+v"(bb6));
        asm("v_permlane32_swap_b32 %0, %1" : "+v"(bb5), "+v"(bb7));
        union U8 { unsigned u[4]; short8 s; };
        U8 p0; p0.u[0] = bb0; p0.u[1] = bb1; p0.u[2] = bb2; p0.u[3] = bb3;
        U8 p1; p1.u[0] = bb4; p1.u[1] = bb5; p1.u[2] = bb6; p1.u[3] = bb7;

        // O^T += V^T * P^T
        o0 = __builtin_amdgcn_mfma_f32_32x32x16_bf16(vc0, p0.s, o0, 0, 0, 0);
        o0 = __builtin_amdgcn_mfma_f32_32x32x16_bf16(vc1, p1.s, o0, 0, 0, 0);
        o1 = __builtin_amdgcn_mfma_f32_32x32x16_bf16(vc2, p0.s, o1, 0, 0, 0);
        o1 = __builtin_amdgcn_mfma_f32_32x32x16_bf16(vc3, p1.s, o1, 0, 0, 0);

        kc0 = kn0; kc1 = kn1; kc2 = kn2; kc3 = kn3;
        vc0 = vn0; vc1 = vn1; vc2 = vn2; vc3 = vn3;
    }

    // store partial: Opart[(b*NTASK+s)][q32][h] bf16
    size_t tbase = ((size_t)(b * NTASK + s) * 32 + q32) * 64;
#pragma unroll
    for (int hb = 0; hb < 2; hb++) {
#pragma unroll
        for (int g = 0; g < 4; g++) {
            float e0 = hb ? o1[4 * g] : o0[4 * g];
            float e1 = hb ? o1[4 * g + 1] : o0[4 * g + 1];
            float e2 = hb ? o1[4 * g + 2] : o0[4 * g + 2];
            float e3 = hb ? o1[4 * g + 3] : o0[4 * g + 3];
            unsigned w0, w1;
            asm("v_cvt_pk_bf16_f32 %0, %1, %2" : "=v"(w0) : "v"(e0), "v"(e1));
            asm("v_cvt_pk_bf16_f32 %0, %1, %2" : "=v"(w1) : "v"(e2), "v"(e3));
            int h0 = hb * 32 + g * 8 + hi * 4;
            *reinterpret_cast<uint2*>(Opart + tbase + h0) = make_uint2(w0, w1);
        }
    }
    if (lane < 32) {
        Mpart[(b * NTASK + s) * 32 + q32] = m;
        Lpart[(b * NTASK + s) * 32 + q32] = l;
    }
}

// ---------------- kernel 3: merge per-chunk partials, divide by l
__global__ __launch_bounds__(256) void attn_merge(const unsigned short* __restrict__ Opart,
                                                  const float* __restrict__ Mpart,
                                                  const float* __restrict__ Lpart,
                                                  float* __restrict__ out) {
    int tid = threadIdx.x;
    int g = blockIdx.x * 64 + (tid >> 2);   // global row
    int h0 = (tid & 3) * 16;
    int b = g >> 12, t = g & 4095;
    int tile = t >> 5, r32 = t & 31;
    int k = tile >> 4;
    int nch = k + 1;
    int s0 = 16 * (36 - (((k + 1) * (k + 2)) >> 1)) + (15 - (tile & 15)) * nch;
    int tb = b * NTASK + s0;

    float mm = -3e38f;
    for (int i = 0; i < nch; i++) mm = fmaxf(mm, Mpart[(tb + i) * 32 + r32]);
    float ll = 0.f;
    float acc[16];
#pragma unroll
    for (int e = 0; e < 16; e++) acc[e] = 0.f;
    for (int i = 0; i < nch; i++) {
        float a = exp2f(Mpart[(tb + i) * 32 + r32] - mm);
        ll += a * Lpart[(tb + i) * 32 + r32];
        const unsigned short* op = Opart + ((size_t)(tb + i) * 32 + r32) * 64 + h0;
        short8 v0 = *(const short8*)op;
        short8 v1 = *(const short8*)(op + 8);
#pragma unroll
        for (int e = 0; e < 8; e++) {
            acc[e]     += a * bf16_to_f32((unsigned short)v0[e]);
            acc[8 + e] += a * bf16_to_f32((unsigned short)v1[e]);
        }
    }
    float inv = 1.f / ll;
    float* dst = out + (size_t)g * 64 + h0;
#pragma unroll
    for (int e = 0; e < 16; e++) dst[e] = acc[e] * inv;
}

extern "C" void kernel_launch(void* const* d_in, const int* in_sizes, int n_in,
                              void* d_out, int out_size, void* d_ws, size_t ws_size,
                              hipStream_t stream) {
    (void)in_sizes; (void)n_in; (void)out_size; (void)ws_size;
    const float* x  = (const float*)d_in[0];
    const float* Wk = (const float*)d_in[1];
    const float* Wq = (const float*)d_in[2];
    const float* Wv = (const float*)d_in[3];
    float* out = (float*)d_out;

    unsigned short* Wb = (unsigned short*)d_ws;              // 192*1024 (swizzled)
    unsigned short* Kb = Wb + 196608;                        // 16384*64
    unsigned short* Qb = Kb + 1048576;                       // pre-scaled by QSCALE
    unsigned short* Vt = Qb + 1048576;                       // (b, 64, t)
    unsigned short* Opart = Vt + 1048576;                    // [4*576][32][64] bf16
    float* Mpart = (float*)(Opart + (size_t)4 * NTASK * 32 * 64);
    float* Lpart = Mpart + 4 * NTASK * 32;

    hipLaunchKernelGGL(convert_w, dim3(96), dim3(256), 0, stream, Wk, Wq, Wv, Wb);
    hipLaunchKernelGGL(qkv_proj, dim3(512), dim3(256), 0, stream, x, Wb, Kb, Qb, Vt);
    hipLaunchKernelGGL(attn, dim3(NTASK, 4), dim3(64), 0, stream, Qb, Kb, Vt, Opart, Mpart, Lpart);
    hipLaunchKernelGGL(attn_merge, dim3(256), dim3(256), 0, stream, Opart, Mpart, Lpart, out);
}